// Round 1
// baseline (3980.460 us; speedup 1.0000x reference)
//
#include <hip/hip_runtime.h>
#include <cstddef>

static constexpr int BTOT = 131072;     // B*T
static constexpr int RESO_ = 128;
static constexpr int R2_ = RESO_ * RESO_;   // 16384
static constexpr int NBIN = 4 * R2_;        // B*R2 = 65536
static constexpr int HDIM = 128;
static constexpr int CDIM = 64;

// ---------- monotone float <-> uint mapping for atomicMax ----------
__device__ __forceinline__ unsigned fmapu(float f) {
  unsigned u = __float_as_uint(f);
  return (u & 0x80000000u) ? ~u : (u | 0x80000000u);
}
__device__ __forceinline__ float funmapu(unsigned u) {
  return __uint_as_float((u & 0x80000000u) ? (u ^ 0x80000000u) : ~u);
}

// ---------- bin indices for the 3 planes ----------
__global__ __launch_bounds__(256) void k_idx(const float* __restrict__ p,
                                             int* __restrict__ idx) {
  int pt = blockIdx.x * 256 + threadIdx.x;   // BTOT threads
  const float DIVC = (float)(1.0 + 0.1 + 1e-5);
  const float HI = (float)(1.0 - 1e-5);
  float x = p[pt * 3 + 0], y = p[pt * 3 + 1], z = p[pt * 3 + 2];
  float nx = fminf(fmaxf(x / DIVC + 0.5f, 0.0f), HI);
  float ny = fminf(fmaxf(y / DIVC + 0.5f, 0.0f), HI);
  float nz = fminf(fmaxf(z / DIVC + 0.5f, 0.0f), HI);
  int ix = (int)(nx * (float)RESO_);
  int iy = (int)(ny * (float)RESO_);
  int iz = (int)(nz * (float)RESO_);
  int off = (pt >> 15) * R2_;                 // batch offset (T = 32768)
  idx[0 * BTOT + pt] = ix + RESO_ * iz + off; // xz
  idx[1 * BTOT + pt] = ix + RESO_ * iy + off; // xy
  idx[2 * BTOT + pt] = iy + RESO_ * iz + off; // yz
}

// ---------- fc_pos: [BT,3] @ [3,256] + b -> split into netA(0:128) poolB(128:256)
__global__ __launch_bounds__(256) void k_fcpos(const float* __restrict__ p,
                                               const float* __restrict__ w,
                                               const float* __restrict__ b,
                                               float* __restrict__ netA,
                                               float* __restrict__ poolB) {
  int e = blockIdx.x * 256 + threadIdx.x;    // BTOT*256 threads
  int pt = e >> 8, col = e & 255;
  float x0 = p[pt * 3 + 0], x1 = p[pt * 3 + 1], x2 = p[pt * 3 + 2];
  float v = b[col] + x0 * w[col] + x1 * w[256 + col] + x2 * w[512 + col];
  if (col < HDIM) netA[(size_t)pt * HDIM + col] = v;
  else            poolB[(size_t)pt * HDIM + (col - HDIM)] = v;
}

// ---------- resblock first half: t = relu(x) @ w0 + b0   (x = [netA|poolB], K=256)
__global__ __launch_bounds__(256) void k_rb0(const float* __restrict__ xA,
                                             const float* __restrict__ xB,
                                             const float* __restrict__ w0,
                                             const float* __restrict__ b0,
                                             float* __restrict__ t) {
  __shared__ __align__(16) float xs[8][256];
  int row0 = blockIdx.x * 8;
  int tid = threadIdx.x;
#pragma unroll
  for (int rr = 0; rr < 8; ++rr) {
    float v = (tid < 128) ? xA[(size_t)(row0 + rr) * 128 + tid]
                          : xB[(size_t)(row0 + rr) * 128 + (tid - 128)];
    xs[rr][tid] = fmaxf(v, 0.0f);
  }
  __syncthreads();
  int j = tid & 127;
  int r0 = (tid >> 7) * 4;
  float a0 = 0.f, a1 = 0.f, a2 = 0.f, a3 = 0.f;
  for (int k = 0; k < 256; k += 4) {
    float w_0 = w0[(k + 0) * 128 + j];
    float w_1 = w0[(k + 1) * 128 + j];
    float w_2 = w0[(k + 2) * 128 + j];
    float w_3 = w0[(k + 3) * 128 + j];
    float4 x0 = *(const float4*)&xs[r0 + 0][k];
    float4 x1 = *(const float4*)&xs[r0 + 1][k];
    float4 x2 = *(const float4*)&xs[r0 + 2][k];
    float4 x3 = *(const float4*)&xs[r0 + 3][k];
    a0 = fmaf(x0.x, w_0, fmaf(x0.y, w_1, fmaf(x0.z, w_2, fmaf(x0.w, w_3, a0))));
    a1 = fmaf(x1.x, w_0, fmaf(x1.y, w_1, fmaf(x1.z, w_2, fmaf(x1.w, w_3, a1))));
    a2 = fmaf(x2.x, w_0, fmaf(x2.y, w_1, fmaf(x2.z, w_2, fmaf(x2.w, w_3, a2))));
    a3 = fmaf(x3.x, w_0, fmaf(x3.y, w_1, fmaf(x3.z, w_2, fmaf(x3.w, w_3, a3))));
  }
  float bb = b0[j];
  t[(size_t)(row0 + r0 + 0) * 128 + j] = a0 + bb;
  t[(size_t)(row0 + r0 + 1) * 128 + j] = a1 + bb;
  t[(size_t)(row0 + r0 + 2) * 128 + j] = a2 + bb;
  t[(size_t)(row0 + r0 + 3) * 128 + j] = a3 + bb;
}

// ---------- resblock second half: out = x @ ws + relu(t) @ w1 + b1  (in-place into netA)
__global__ __launch_bounds__(256) void k_rb1(const float* __restrict__ xA,
                                             const float* __restrict__ xB,
                                             const float* __restrict__ t,
                                             const float* __restrict__ w1,
                                             const float* __restrict__ b1,
                                             const float* __restrict__ wsk,
                                             float* __restrict__ outA) {
  __shared__ __align__(16) float xs[8][256];
  __shared__ __align__(16) float ts[8][128];
  int row0 = blockIdx.x * 8;
  int tid = threadIdx.x;
#pragma unroll
  for (int rr = 0; rr < 8; ++rr) {
    float v = (tid < 128) ? xA[(size_t)(row0 + rr) * 128 + tid]
                          : xB[(size_t)(row0 + rr) * 128 + (tid - 128)];
    xs[rr][tid] = v;
  }
#pragma unroll
  for (int rr = 0; rr < 4; ++rr) {
    int e = rr * 256 + tid;
    int r = e >> 7, c = e & 127;
    ts[r][c] = fmaxf(t[(size_t)(row0 + r) * 128 + c], 0.0f);
  }
  __syncthreads();
  int j = tid & 127;
  int r0 = (tid >> 7) * 4;
  float a0 = 0.f, a1 = 0.f, a2 = 0.f, a3 = 0.f;
  for (int k = 0; k < 256; k += 4) {
    float w_0 = wsk[(k + 0) * 128 + j];
    float w_1 = wsk[(k + 1) * 128 + j];
    float w_2 = wsk[(k + 2) * 128 + j];
    float w_3 = wsk[(k + 3) * 128 + j];
    float4 x0 = *(const float4*)&xs[r0 + 0][k];
    float4 x1 = *(const float4*)&xs[r0 + 1][k];
    float4 x2 = *(const float4*)&xs[r0 + 2][k];
    float4 x3 = *(const float4*)&xs[r0 + 3][k];
    a0 = fmaf(x0.x, w_0, fmaf(x0.y, w_1, fmaf(x0.z, w_2, fmaf(x0.w, w_3, a0))));
    a1 = fmaf(x1.x, w_0, fmaf(x1.y, w_1, fmaf(x1.z, w_2, fmaf(x1.w, w_3, a1))));
    a2 = fmaf(x2.x, w_0, fmaf(x2.y, w_1, fmaf(x2.z, w_2, fmaf(x2.w, w_3, a2))));
    a3 = fmaf(x3.x, w_0, fmaf(x3.y, w_1, fmaf(x3.z, w_2, fmaf(x3.w, w_3, a3))));
  }
  for (int k = 0; k < 128; k += 4) {
    float w_0 = w1[(k + 0) * 128 + j];
    float w_1 = w1[(k + 1) * 128 + j];
    float w_2 = w1[(k + 2) * 128 + j];
    float w_3 = w1[(k + 3) * 128 + j];
    float4 t0 = *(const float4*)&ts[r0 + 0][k];
    float4 t1 = *(const float4*)&ts[r0 + 1][k];
    float4 t2 = *(const float4*)&ts[r0 + 2][k];
    float4 t3 = *(const float4*)&ts[r0 + 3][k];
    a0 = fmaf(t0.x, w_0, fmaf(t0.y, w_1, fmaf(t0.z, w_2, fmaf(t0.w, w_3, a0))));
    a1 = fmaf(t1.x, w_0, fmaf(t1.y, w_1, fmaf(t1.z, w_2, fmaf(t1.w, w_3, a1))));
    a2 = fmaf(t2.x, w_0, fmaf(t2.y, w_1, fmaf(t2.z, w_2, fmaf(t2.w, w_3, a2))));
    a3 = fmaf(t3.x, w_0, fmaf(t3.y, w_1, fmaf(t3.z, w_2, fmaf(t3.w, w_3, a3))));
  }
  float bb = b1[j];
  outA[(size_t)(row0 + r0 + 0) * 128 + j] = a0 + bb;
  outA[(size_t)(row0 + r0 + 1) * 128 + j] = a1 + bb;
  outA[(size_t)(row0 + r0 + 2) * 128 + j] = a2 + bb;
  outA[(size_t)(row0 + r0 + 3) * 128 + j] = a3 + bb;
}

// ---------- scatter max (one plane) ----------
__global__ __launch_bounds__(256) void k_scatter_max(const float* __restrict__ net,
                                                     const int* __restrict__ idx,
                                                     unsigned* __restrict__ seg) {
  int e = blockIdx.x * 256 + threadIdx.x;   // BTOT*128 threads
  int pt = e >> 7, ch = e & 127;
  int bin = idx[pt];
  atomicMax(&seg[(size_t)bin * 128 + ch], fmapu(net[e]));
}

// ---------- gather (one plane), accumulate into poolB ----------
__global__ __launch_bounds__(256) void k_gather(const unsigned* __restrict__ seg,
                                                const int* __restrict__ idx,
                                                float* __restrict__ pool,
                                                int accumulate) {
  int e = blockIdx.x * 256 + threadIdx.x;
  int pt = e >> 7, ch = e & 127;
  float v = funmapu(seg[(size_t)idx[pt] * 128 + ch]);
  if (accumulate) pool[e] += v;
  else            pool[e] = v;
}

// ---------- fc_c: c = net @ [128,64] + b ----------
__global__ __launch_bounds__(256) void k_fcc(const float* __restrict__ x,
                                             const float* __restrict__ w,
                                             const float* __restrict__ b,
                                             float* __restrict__ c) {
  __shared__ __align__(16) float xs[16][128];
  int row0 = blockIdx.x * 16;
  int tid = threadIdx.x;
#pragma unroll
  for (int rr = 0; rr < 8; ++rr) {
    int e = rr * 256 + tid;
    int r = e >> 7, cc = e & 127;
    xs[r][cc] = x[(size_t)(row0 + r) * 128 + cc];
  }
  __syncthreads();
  int j = tid & 63;
  int r0 = (tid >> 6) * 4;
  float a0 = 0.f, a1 = 0.f, a2 = 0.f, a3 = 0.f;
  for (int k = 0; k < 128; k += 4) {
    float w_0 = w[(k + 0) * 64 + j];
    float w_1 = w[(k + 1) * 64 + j];
    float w_2 = w[(k + 2) * 64 + j];
    float w_3 = w[(k + 3) * 64 + j];
    float4 x0 = *(const float4*)&xs[r0 + 0][k];
    float4 x1 = *(const float4*)&xs[r0 + 1][k];
    float4 x2 = *(const float4*)&xs[r0 + 2][k];
    float4 x3 = *(const float4*)&xs[r0 + 3][k];
    a0 = fmaf(x0.x, w_0, fmaf(x0.y, w_1, fmaf(x0.z, w_2, fmaf(x0.w, w_3, a0))));
    a1 = fmaf(x1.x, w_0, fmaf(x1.y, w_1, fmaf(x1.z, w_2, fmaf(x1.w, w_3, a1))));
    a2 = fmaf(x2.x, w_0, fmaf(x2.y, w_1, fmaf(x2.z, w_2, fmaf(x2.w, w_3, a2))));
    a3 = fmaf(x3.x, w_0, fmaf(x3.y, w_1, fmaf(x3.z, w_2, fmaf(x3.w, w_3, a3))));
  }
  float bb = b[j];
  c[(size_t)(row0 + r0 + 0) * 64 + j] = a0 + bb;
  c[(size_t)(row0 + r0 + 1) * 64 + j] = a1 + bb;
  c[(size_t)(row0 + r0 + 2) * 64 + j] = a2 + bb;
  c[(size_t)(row0 + r0 + 3) * 64 + j] = a3 + bb;
}

// ---------- scatter mean accumulation (one plane) ----------
__global__ __launch_bounds__(256) void k_smean(const float* __restrict__ c,
                                               const int* __restrict__ idx,
                                               float* __restrict__ sums,
                                               float* __restrict__ cnt) {
  int e = blockIdx.x * 256 + threadIdx.x;   // BTOT*64 threads
  int pt = e >> 6, ch = e & 63;
  int bin = idx[pt];
  atomicAdd(&sums[(size_t)bin * 64 + ch], c[e]);
  if (ch == 0) atomicAdd(&cnt[bin], 1.0f);
}

// ---------- finalize: out[b][ch][bin] = sums[b*R2+bin][ch] / max(cnt,1) ----------
__global__ __launch_bounds__(256) void k_final(const float* __restrict__ sums,
                                               const float* __restrict__ cnt,
                                               float* __restrict__ outp) {
  __shared__ float tile[64][65];
  __shared__ float cinv[64];
  int b = blockIdx.y;
  int bin0 = blockIdx.x * 64;
  int tid = threadIdx.x;
#pragma unroll
  for (int i = 0; i < 16; ++i) {
    int e = i * 256 + tid;
    int lb = e >> 6, lc = e & 63;
    tile[lb][lc] = sums[((size_t)(b * R2_ + bin0 + lb)) * 64 + lc];
  }
  if (tid < 64) {
    float c = cnt[b * R2_ + bin0 + tid];
    cinv[tid] = 1.0f / fmaxf(c, 1.0f);
  }
  __syncthreads();
#pragma unroll
  for (int i = 0; i < 16; ++i) {
    int e = i * 256 + tid;
    int ch = e >> 6, lb = e & 63;
    outp[((size_t)(b * 64 + ch)) * R2_ + bin0 + lb] = tile[lb][ch] * cinv[lb];
  }
}

extern "C" void kernel_launch(void* const* d_in, const int* in_sizes, int n_in,
                              void* d_out, int out_size, void* d_ws, size_t ws_size,
                              hipStream_t stream) {
  const float* p    = (const float*)d_in[0];
  const float* fcw  = (const float*)d_in[1];
  const float* fcb  = (const float*)d_in[2];
  const float* bw0  = (const float*)d_in[3];
  const float* bb0  = (const float*)d_in[4];
  const float* bw1  = (const float*)d_in[5];
  const float* bb1  = (const float*)d_in[6];
  const float* bws  = (const float*)d_in[7];
  const float* fccw = (const float*)d_in[8];
  const float* fccb = (const float*)d_in[9];
  float* out = (float*)d_out;

  char* ws = (char*)d_ws;
  const size_t SZ128 = (size_t)BTOT * 128 * 4;   // 64 MiB
  float* netA  = (float*)(ws);
  float* poolB = (float*)(ws + SZ128);
  float* tbuf  = (float*)(ws + 2 * SZ128);
  int*   idx   = (int*)  (ws + 3 * SZ128);
  unsigned* seg = (unsigned*)(ws + 3 * SZ128 + (size_t)3 * BTOT * 4);
  float* sums = (float*)seg;
  float* cnt  = (float*)((char*)seg + (size_t)NBIN * CDIM * 4);
  float* cbuf = tbuf;  // reuse t buffer for c

  k_idx<<<BTOT / 256, 256, 0, stream>>>(p, idx);
  k_fcpos<<<BTOT, 256, 0, stream>>>(p, fcw, fcb, netA, poolB);

  for (int blk = 0; blk < 5; ++blk) {
    if (blk > 0) {
      for (int pl = 0; pl < 3; ++pl) {
        hipMemsetAsync(seg, 0, (size_t)NBIN * HDIM * 4, stream);
        k_scatter_max<<<BTOT * HDIM / 256, 256, 0, stream>>>(netA, idx + pl * BTOT, seg);
        k_gather<<<BTOT * HDIM / 256, 256, 0, stream>>>(seg, idx + pl * BTOT, poolB, pl);
      }
    }
    k_rb0<<<BTOT / 8, 256, 0, stream>>>(netA, poolB,
                                        bw0 + (size_t)blk * 256 * 128,
                                        bb0 + (size_t)blk * 128, tbuf);
    k_rb1<<<BTOT / 8, 256, 0, stream>>>(netA, poolB, tbuf,
                                        bw1 + (size_t)blk * 128 * 128,
                                        bb1 + (size_t)blk * 128,
                                        bws + (size_t)blk * 256 * 128, netA);
  }

  k_fcc<<<BTOT / 16, 256, 0, stream>>>(netA, fccw, fccb, cbuf);

  for (int pl = 0; pl < 3; ++pl) {
    hipMemsetAsync(sums, 0, (size_t)NBIN * CDIM * 4 + (size_t)NBIN * 4, stream);
    k_smean<<<BTOT * CDIM / 256, 256, 0, stream>>>(cbuf, idx + pl * BTOT, sums, cnt);
    dim3 g(R2_ / 64, 4);
    k_final<<<g, 256, 0, stream>>>(sums, cnt, out + (size_t)pl * 4 * CDIM * R2_);
  }
}

// Round 2
// 1758.918 us; speedup vs baseline: 2.2630x; 2.2630x over previous
//
#include <hip/hip_runtime.h>
#include <cstddef>

static constexpr int BTOT = 131072;     // B*T
static constexpr int RESO_ = 128;
static constexpr int R2_ = RESO_ * RESO_;   // 16384
static constexpr int NBIN = 4 * R2_;        // B*R2 = 65536
static constexpr int HDIM = 128;
static constexpr int CDIM = 64;

typedef __attribute__((ext_vector_type(8))) short short8;
typedef __attribute__((ext_vector_type(4))) short short4v;
typedef __attribute__((ext_vector_type(4))) float floatx4;

// ---------- bf16 helpers ----------
__device__ __forceinline__ unsigned short f2bf_rtn(float f) {
  unsigned u = __float_as_uint(f);
  unsigned r = u + 0x7FFFu + ((u >> 16) & 1u);
  return (unsigned short)(r >> 16);
}
__device__ __forceinline__ float bf2f(unsigned short h) {
  return __uint_as_float(((unsigned)h) << 16);
}
__device__ __forceinline__ short8 relu8(short8 v) {
#pragma unroll
  for (int i = 0; i < 8; ++i) v[i] = (v[i] < (short)0) ? (short)0 : v[i];
  return v;
}

// ---------- monotone float <-> uint mapping for atomicMax ----------
__device__ __forceinline__ unsigned fmapu(float f) {
  unsigned u = __float_as_uint(f);
  return (u & 0x80000000u) ? ~u : (u | 0x80000000u);
}
__device__ __forceinline__ float funmapu(unsigned u) {
  return __uint_as_float((u & 0x80000000u) ? (u ^ 0x80000000u) : ~u);
}

// ---------- bin indices for the 3 planes ----------
__global__ __launch_bounds__(256) void k_idx(const float* __restrict__ p,
                                             int* __restrict__ idx) {
  int pt = blockIdx.x * 256 + threadIdx.x;
  const float DIVC = (float)(1.0 + 0.1 + 1e-5);
  const float HI = (float)(1.0 - 1e-5);
  float x = p[pt * 3 + 0], y = p[pt * 3 + 1], z = p[pt * 3 + 2];
  float nx = fminf(fmaxf(x / DIVC + 0.5f, 0.0f), HI);
  float ny = fminf(fmaxf(y / DIVC + 0.5f, 0.0f), HI);
  float nz = fminf(fmaxf(z / DIVC + 0.5f, 0.0f), HI);
  int ix = (int)(nx * (float)RESO_);
  int iy = (int)(ny * (float)RESO_);
  int iz = (int)(nz * (float)RESO_);
  int off = (pt >> 15) * R2_;
  idx[0 * BTOT + pt] = ix + RESO_ * iz + off; // xz
  idx[1 * BTOT + pt] = ix + RESO_ * iy + off; // xy
  idx[2 * BTOT + pt] = iy + RESO_ * iz + off; // yz
}

// ---------- fc_pos ----------
__global__ __launch_bounds__(256) void k_fcpos(const float* __restrict__ p,
                                               const float* __restrict__ w,
                                               const float* __restrict__ b,
                                               float* __restrict__ netA,
                                               float* __restrict__ poolB) {
  int e = blockIdx.x * 256 + threadIdx.x;
  int pt = e >> 8, col = e & 255;
  float x0 = p[pt * 3 + 0], x1 = p[pt * 3 + 1], x2 = p[pt * 3 + 2];
  float v = b[col] + x0 * w[col] + x1 * w[256 + col] + x2 * w[512 + col];
  if (col < HDIM) netA[(size_t)pt * HDIM + col] = v;
  else            poolB[(size_t)pt * HDIM + (col - HDIM)] = v;
}

// ---------- weight packing into MFMA B-fragment order (bf16 hi/lo split) ----
// P1: per layer, w0 [256x128]: kb in [0,8), nt in [0,8), lane, j
//     value = w0[kb*32 + (lane>>4)*8 + j][nt*16 + (lane&15)]
// P2: per layer, concat_k(ws [256x128], w1 [128x128]): kb in [0,12)
__global__ __launch_bounds__(256) void k_pack(const float* __restrict__ bw0,
                                              const float* __restrict__ bw1,
                                              const float* __restrict__ bws,
                                              unsigned short* __restrict__ P1H,
                                              unsigned short* __restrict__ P1L,
                                              unsigned short* __restrict__ P2H,
                                              unsigned short* __restrict__ P2L) {
  int t = blockIdx.x * 256 + threadIdx.x;
  if (t >= 5 * 20 * 8 * 64) return;
  int lane = t & 63;
  int r = t >> 6;
  int nt = r & 7; r >>= 3;
  int kb20 = r % 20;
  int l = r / 20;
  int quad = lane >> 4;
  int n = nt * 16 + (lane & 15);
#pragma unroll
  for (int j = 0; j < 8; ++j) {
    if (kb20 < 8) {
      int k = kb20 * 32 + quad * 8 + j;
      float v = bw0[((size_t)l * 256 + k) * 128 + n];
      size_t didx = (((size_t)(l * 8 + kb20) * 8 + nt) * 64 + lane) * 8 + j;
      unsigned short h = f2bf_rtn(v);
      P1H[didx] = h;
      P1L[didx] = f2bf_rtn(v - bf2f(h));
    } else {
      int kb = kb20 - 8;
      int k = kb * 32 + quad * 8 + j;
      float v = (k < 256) ? bws[((size_t)l * 256 + k) * 128 + n]
                          : bw1[((size_t)l * 128 + (k - 256)) * 128 + n];
      size_t didx = (((size_t)(l * 12 + kb) * 8 + nt) * 64 + lane) * 8 + j;
      unsigned short h = f2bf_rtn(v);
      P2H[didx] = h;
      P2L[didx] = f2bf_rtn(v - bf2f(h));
    }
  }
}

// ---------- fused resblock: xA <- x@ws + relu(relu(x)@w0+b0)@w1 + b1 ----------
// x = [xA | xB], row-local. MFMA 16x16x32 bf16 with hi/lo split (3 mfma/term).
__global__ __launch_bounds__(256) void k_resblock(
    const float* __restrict__ xB, float* __restrict__ xA,
    const unsigned short* __restrict__ P1H, const unsigned short* __restrict__ P1L,
    const unsigned short* __restrict__ P2H, const unsigned short* __restrict__ P2L,
    const float* __restrict__ b0, const float* __restrict__ b1) {
  __shared__ __align__(16) unsigned short xh[32][264];
  __shared__ __align__(16) unsigned short xl[32][264];
  __shared__ __align__(16) unsigned short th[32][136];
  __shared__ __align__(16) unsigned short tl[32][136];
  int tid = threadIdx.x;
  int row0 = blockIdx.x * 32;

  // stage A: global fp32 -> LDS bf16 hi/lo (raw x, no relu)
#pragma unroll
  for (int i = 0; i < 8; ++i) {
    int f4 = i * 256 + tid;
    int row = f4 >> 6;
    int col = (f4 & 63) * 4;
    const float* src = (col < 128) ? (xA + (size_t)(row0 + row) * 128 + col)
                                   : (xB + (size_t)(row0 + row) * 128 + (col - 128));
    float4 f = *(const float4*)src;
    short4v hv, lv;
    float vs[4] = {f.x, f.y, f.z, f.w};
#pragma unroll
    for (int q = 0; q < 4; ++q) {
      unsigned short h = f2bf_rtn(vs[q]);
      hv[q] = (short)h;
      lv[q] = (short)f2bf_rtn(vs[q] - bf2f(h));
    }
    *(short4v*)&xh[row][col] = hv;
    *(short4v*)&xl[row][col] = lv;
  }
  __syncthreads();

  int lane = tid & 63;
  int wv = tid >> 6;
  int r0 = (wv & 1) * 16;          // wave's 16-row strip
  int cg = wv >> 1;                // wave's 64-col group
  int quad = lane >> 4;
  int m = r0 + (lane & 15);

  // ---- stage 1: t = relu(x) @ w0 + b0 ----
  floatx4 acc[4] = {{0,0,0,0},{0,0,0,0},{0,0,0,0},{0,0,0,0}};
  for (int kb = 0; kb < 8; ++kb) {
    short8 ah = relu8(*(const short8*)&xh[m][kb * 32 + quad * 8]);
    short8 al = relu8(*(const short8*)&xl[m][kb * 32 + quad * 8]);
    const short8* wh = (const short8*)P1H + ((size_t)(kb * 8 + cg * 4) * 64 + lane);
    const short8* wl = (const short8*)P1L + ((size_t)(kb * 8 + cg * 4) * 64 + lane);
#pragma unroll
    for (int nti = 0; nti < 4; ++nti) {
      short8 bh = wh[nti * 64];
      short8 bl = wl[nti * 64];
      acc[nti] = __builtin_amdgcn_mfma_f32_16x16x32_bf16(ah, bh, acc[nti], 0, 0, 0);
      acc[nti] = __builtin_amdgcn_mfma_f32_16x16x32_bf16(ah, bl, acc[nti], 0, 0, 0);
      acc[nti] = __builtin_amdgcn_mfma_f32_16x16x32_bf16(al, bh, acc[nti], 0, 0, 0);
    }
  }
  // epilogue 1: bias + relu + split -> LDS (relu BEFORE split: exact)
#pragma unroll
  for (int nti = 0; nti < 4; ++nti) {
    int col = cg * 64 + nti * 16 + (lane & 15);
    float bb = b0[col];
#pragma unroll
    for (int r = 0; r < 4; ++r) {
      int row = r0 + quad * 4 + r;
      float v = fmaxf(acc[nti][r] + bb, 0.0f);
      unsigned short h = f2bf_rtn(v);
      th[row][col] = h;
      tl[row][col] = f2bf_rtn(v - bf2f(h));
    }
  }
  __syncthreads();

  // ---- stage 2: out = x @ ws + relu_t @ w1 + b1 ----
  floatx4 acc2[4] = {{0,0,0,0},{0,0,0,0},{0,0,0,0},{0,0,0,0}};
  for (int kb = 0; kb < 8; ++kb) {           // K-part A: raw x vs ws
    short8 ah = *(const short8*)&xh[m][kb * 32 + quad * 8];
    short8 al = *(const short8*)&xl[m][kb * 32 + quad * 8];
    const short8* wh = (const short8*)P2H + ((size_t)(kb * 8 + cg * 4) * 64 + lane);
    const short8* wl = (const short8*)P2L + ((size_t)(kb * 8 + cg * 4) * 64 + lane);
#pragma unroll
    for (int nti = 0; nti < 4; ++nti) {
      short8 bh = wh[nti * 64];
      short8 bl = wl[nti * 64];
      acc2[nti] = __builtin_amdgcn_mfma_f32_16x16x32_bf16(ah, bh, acc2[nti], 0, 0, 0);
      acc2[nti] = __builtin_amdgcn_mfma_f32_16x16x32_bf16(ah, bl, acc2[nti], 0, 0, 0);
      acc2[nti] = __builtin_amdgcn_mfma_f32_16x16x32_bf16(al, bh, acc2[nti], 0, 0, 0);
    }
  }
  for (int kb = 0; kb < 4; ++kb) {           // K-part B: relu_t vs w1
    short8 ah = *(const short8*)&th[m][kb * 32 + quad * 8];
    short8 al = *(const short8*)&tl[m][kb * 32 + quad * 8];
    const short8* wh = (const short8*)P2H + ((size_t)((8 + kb) * 8 + cg * 4) * 64 + lane);
    const short8* wl = (const short8*)P2L + ((size_t)((8 + kb) * 8 + cg * 4) * 64 + lane);
#pragma unroll
    for (int nti = 0; nti < 4; ++nti) {
      short8 bh = wh[nti * 64];
      short8 bl = wl[nti * 64];
      acc2[nti] = __builtin_amdgcn_mfma_f32_16x16x32_bf16(ah, bh, acc2[nti], 0, 0, 0);
      acc2[nti] = __builtin_amdgcn_mfma_f32_16x16x32_bf16(ah, bl, acc2[nti], 0, 0, 0);
      acc2[nti] = __builtin_amdgcn_mfma_f32_16x16x32_bf16(al, bh, acc2[nti], 0, 0, 0);
    }
  }
  // epilogue 2: bias + store (in-place into xA; block owns its rows)
#pragma unroll
  for (int nti = 0; nti < 4; ++nti) {
    int col = cg * 64 + nti * 16 + (lane & 15);
    float bb = b1[col];
#pragma unroll
    for (int r = 0; r < 4; ++r) {
      int row = row0 + r0 + quad * 4 + r;
      xA[(size_t)row * 128 + col] = acc2[nti][r] + bb;
    }
  }
}

// ---------- fused 3-plane scatter max, half the channels per pass ----------
__global__ __launch_bounds__(256) void k_scatter3h(const float* __restrict__ net,
                                                   const int* __restrict__ idx,
                                                   unsigned* __restrict__ seg,
                                                   int half) {
  int e = blockIdx.x * 256 + threadIdx.x;   // BTOT*64 threads
  int pt = e >> 6, ch = e & 63;
  unsigned v = fmapu(net[(size_t)pt * 128 + half * 64 + ch]);
  int i0 = idx[pt], i1 = idx[BTOT + pt], i2 = idx[2 * BTOT + pt];
  atomicMax(&seg[(size_t)i0 * 64 + ch], v);
  atomicMax(&seg[(size_t)NBIN * 64 + (size_t)i1 * 64 + ch], v);
  atomicMax(&seg[(size_t)2 * NBIN * 64 + (size_t)i2 * 64 + ch], v);
}

__global__ __launch_bounds__(256) void k_gather3h(const unsigned* __restrict__ seg,
                                                  const int* __restrict__ idx,
                                                  float* __restrict__ pool,
                                                  int half) {
  int e = blockIdx.x * 256 + threadIdx.x;
  int pt = e >> 6, ch = e & 63;
  int i0 = idx[pt], i1 = idx[BTOT + pt], i2 = idx[2 * BTOT + pt];
  float v = funmapu(seg[(size_t)i0 * 64 + ch])
          + funmapu(seg[(size_t)NBIN * 64 + (size_t)i1 * 64 + ch])
          + funmapu(seg[(size_t)2 * NBIN * 64 + (size_t)i2 * 64 + ch]);
  pool[(size_t)pt * 128 + half * 64 + ch] = v;
}

// ---------- fc_c ----------
__global__ __launch_bounds__(256) void k_fcc(const float* __restrict__ x,
                                             const float* __restrict__ w,
                                             const float* __restrict__ b,
                                             float* __restrict__ c) {
  __shared__ __align__(16) float xs[16][128];
  int row0 = blockIdx.x * 16;
  int tid = threadIdx.x;
#pragma unroll
  for (int rr = 0; rr < 8; ++rr) {
    int e = rr * 256 + tid;
    int r = e >> 7, cc = e & 127;
    xs[r][cc] = x[(size_t)(row0 + r) * 128 + cc];
  }
  __syncthreads();
  int j = tid & 63;
  int r0 = (tid >> 6) * 4;
  float a0 = 0.f, a1 = 0.f, a2 = 0.f, a3 = 0.f;
  for (int k = 0; k < 128; k += 4) {
    float w_0 = w[(k + 0) * 64 + j];
    float w_1 = w[(k + 1) * 64 + j];
    float w_2 = w[(k + 2) * 64 + j];
    float w_3 = w[(k + 3) * 64 + j];
    float4 x0 = *(const float4*)&xs[r0 + 0][k];
    float4 x1 = *(const float4*)&xs[r0 + 1][k];
    float4 x2 = *(const float4*)&xs[r0 + 2][k];
    float4 x3 = *(const float4*)&xs[r0 + 3][k];
    a0 = fmaf(x0.x, w_0, fmaf(x0.y, w_1, fmaf(x0.z, w_2, fmaf(x0.w, w_3, a0))));
    a1 = fmaf(x1.x, w_0, fmaf(x1.y, w_1, fmaf(x1.z, w_2, fmaf(x1.w, w_3, a1))));
    a2 = fmaf(x2.x, w_0, fmaf(x2.y, w_1, fmaf(x2.z, w_2, fmaf(x2.w, w_3, a2))));
    a3 = fmaf(x3.x, w_0, fmaf(x3.y, w_1, fmaf(x3.z, w_2, fmaf(x3.w, w_3, a3))));
  }
  float bb = b[j];
  c[(size_t)(row0 + r0 + 0) * 64 + j] = a0 + bb;
  c[(size_t)(row0 + r0 + 1) * 64 + j] = a1 + bb;
  c[(size_t)(row0 + r0 + 2) * 64 + j] = a2 + bb;
  c[(size_t)(row0 + r0 + 3) * 64 + j] = a3 + bb;
}

// ---------- scatter mean accumulation (one plane) ----------
__global__ __launch_bounds__(256) void k_smean(const float* __restrict__ c,
                                               const int* __restrict__ idx,
                                               float* __restrict__ sums,
                                               float* __restrict__ cnt) {
  int e = blockIdx.x * 256 + threadIdx.x;
  int pt = e >> 6, ch = e & 63;
  int bin = idx[pt];
  atomicAdd(&sums[(size_t)bin * 64 + ch], c[e]);
  if (ch == 0) atomicAdd(&cnt[bin], 1.0f);
}

// ---------- finalize ----------
__global__ __launch_bounds__(256) void k_final(const float* __restrict__ sums,
                                               const float* __restrict__ cnt,
                                               float* __restrict__ outp) {
  __shared__ float tile[64][65];
  __shared__ float cinv[64];
  int b = blockIdx.y;
  int bin0 = blockIdx.x * 64;
  int tid = threadIdx.x;
#pragma unroll
  for (int i = 0; i < 16; ++i) {
    int e = i * 256 + tid;
    int lb = e >> 6, lc = e & 63;
    tile[lb][lc] = sums[((size_t)(b * R2_ + bin0 + lb)) * 64 + lc];
  }
  if (tid < 64) {
    float c = cnt[b * R2_ + bin0 + tid];
    cinv[tid] = 1.0f / fmaxf(c, 1.0f);
  }
  __syncthreads();
#pragma unroll
  for (int i = 0; i < 16; ++i) {
    int e = i * 256 + tid;
    int ch = e >> 6, lb = e & 63;
    outp[((size_t)(b * 64 + ch)) * R2_ + bin0 + lb] = tile[lb][ch] * cinv[lb];
  }
}

extern "C" void kernel_launch(void* const* d_in, const int* in_sizes, int n_in,
                              void* d_out, int out_size, void* d_ws, size_t ws_size,
                              hipStream_t stream) {
  const float* p    = (const float*)d_in[0];
  const float* fcw  = (const float*)d_in[1];
  const float* fcb  = (const float*)d_in[2];
  const float* bw0  = (const float*)d_in[3];
  const float* bb0  = (const float*)d_in[4];
  const float* bw1  = (const float*)d_in[5];
  const float* bb1  = (const float*)d_in[6];
  const float* bws  = (const float*)d_in[7];
  const float* fccw = (const float*)d_in[8];
  const float* fccb = (const float*)d_in[9];
  float* out = (float*)d_out;

  char* ws = (char*)d_ws;
  const size_t SZ128 = (size_t)BTOT * 128 * 4;          // 64 MiB
  const size_t P1_LAYER = 8 * 8 * 64 * 8;               // shorts
  const size_t P2_LAYER = 12 * 8 * 64 * 8;              // shorts

  float* netA  = (float*)(ws);
  float* poolB = (float*)(ws + SZ128);
  int*   idx   = (int*)  (ws + 2 * SZ128);
  size_t off = 2 * SZ128 + (size_t)3 * BTOT * 4;
  unsigned short* P1H = (unsigned short*)(ws + off); off += 5 * P1_LAYER * 2;
  unsigned short* P1L = (unsigned short*)(ws + off); off += 5 * P1_LAYER * 2;
  unsigned short* P2H = (unsigned short*)(ws + off); off += 5 * P2_LAYER * 2;
  unsigned short* P2L = (unsigned short*)(ws + off); off += 5 * P2_LAYER * 2;
  off = (off + 255) & ~(size_t)255;
  unsigned* seg = (unsigned*)(ws + off);                // 3*NBIN*64*4 = 48 MiB
  float* sums = (float*)seg;
  float* cnt  = (float*)((char*)seg + (size_t)NBIN * CDIM * 4);
  float* cbuf = poolB;                                  // reuse after pooling done

  k_pack<<<200, 256, 0, stream>>>(bw0, bw1, bws, P1H, P1L, P2H, P2L);
  k_idx<<<BTOT / 256, 256, 0, stream>>>(p, idx);
  k_fcpos<<<BTOT, 256, 0, stream>>>(p, fcw, fcb, netA, poolB);

  for (int blk = 0; blk < 5; ++blk) {
    if (blk > 0) {
      for (int half = 0; half < 2; ++half) {
        hipMemsetAsync(seg, 0, (size_t)3 * NBIN * 64 * 4, stream);
        k_scatter3h<<<BTOT * 64 / 256, 256, 0, stream>>>(netA, idx, seg, half);
        k_gather3h<<<BTOT * 64 / 256, 256, 0, stream>>>(seg, idx, poolB, half);
      }
    }
    k_resblock<<<BTOT / 32, 256, 0, stream>>>(
        poolB, netA,
        P1H + (size_t)blk * P1_LAYER, P1L + (size_t)blk * P1_LAYER,
        P2H + (size_t)blk * P2_LAYER, P2L + (size_t)blk * P2_LAYER,
        bb0 + (size_t)blk * 128, bb1 + (size_t)blk * 128);
  }

  k_fcc<<<BTOT / 16, 256, 0, stream>>>(netA, fccw, fccb, cbuf);

  for (int pl = 0; pl < 3; ++pl) {
    hipMemsetAsync(sums, 0, (size_t)NBIN * CDIM * 4 + (size_t)NBIN * 4, stream);
    k_smean<<<BTOT * CDIM / 256, 256, 0, stream>>>(cbuf, idx + (size_t)pl * BTOT, sums, cnt);
    dim3 g(R2_ / 64, 4);
    k_final<<<g, 256, 0, stream>>>(sums, cnt, out + (size_t)pl * 4 * CDIM * R2_);
  }
}

// Round 3
// 1400.643 us; speedup vs baseline: 2.8419x; 1.2558x over previous
//
#include <hip/hip_runtime.h>
#include <cstddef>

static constexpr int BTOT = 131072;     // B*T
static constexpr int RESO_ = 128;
static constexpr int R2_ = RESO_ * RESO_;   // 16384
static constexpr int NBIN = 4 * R2_;        // B*R2 = 65536
static constexpr int HDIM = 128;
static constexpr int CDIM = 64;

typedef __attribute__((ext_vector_type(8))) short short8;
typedef __attribute__((ext_vector_type(4))) short short4v;
typedef __attribute__((ext_vector_type(4))) float floatx4;

// ---------- bf16 helpers ----------
__device__ __forceinline__ unsigned short f2bf_rtn(float f) {
  unsigned u = __float_as_uint(f);
  unsigned r = u + 0x7FFFu + ((u >> 16) & 1u);
  return (unsigned short)(r >> 16);
}
__device__ __forceinline__ float bf2f(unsigned short h) {
  return __uint_as_float(((unsigned)h) << 16);
}
__device__ __forceinline__ short8 relu8(short8 v) {
#pragma unroll
  for (int i = 0; i < 8; ++i) v[i] = (v[i] < (short)0) ? (short)0 : v[i];
  return v;
}

// ---------- bin indices for the 3 planes ----------
__global__ __launch_bounds__(256) void k_idx(const float* __restrict__ p,
                                             int* __restrict__ idx) {
  int pt = blockIdx.x * 256 + threadIdx.x;
  const float DIVC = (float)(1.0 + 0.1 + 1e-5);
  const float HI = (float)(1.0 - 1e-5);
  float x = p[pt * 3 + 0], y = p[pt * 3 + 1], z = p[pt * 3 + 2];
  float nx = fminf(fmaxf(x / DIVC + 0.5f, 0.0f), HI);
  float ny = fminf(fmaxf(y / DIVC + 0.5f, 0.0f), HI);
  float nz = fminf(fmaxf(z / DIVC + 0.5f, 0.0f), HI);
  int ix = (int)(nx * (float)RESO_);
  int iy = (int)(ny * (float)RESO_);
  int iz = (int)(nz * (float)RESO_);
  int off = (pt >> 15) * R2_;
  idx[0 * BTOT + pt] = ix + RESO_ * iz + off; // xz
  idx[1 * BTOT + pt] = ix + RESO_ * iy + off; // xy
  idx[2 * BTOT + pt] = iy + RESO_ * iz + off; // yz
}

// ---------- bin list construction ----------
__global__ __launch_bounds__(256) void k_count(const int* __restrict__ idx,
                                               int* __restrict__ cnt) {
  int e = blockIdx.x * 256 + threadIdx.x;    // 3*BTOT
  int pl = e / BTOT;
  atomicAdd(&cnt[pl * NBIN + idx[e]], 1);
}

__global__ __launch_bounds__(1024) void k_scan(const int* __restrict__ cnt,
                                               int* __restrict__ starts,
                                               int* __restrict__ cursor) {
  __shared__ int part[1024];
  int pl = blockIdx.x;
  int t = threadIdx.x;
  const int* c = cnt + pl * NBIN;
  int base = t * 64;
  int s = 0;
  for (int i = 0; i < 64; ++i) s += c[base + i];
  part[t] = s;
  __syncthreads();
  for (int off = 1; off < 1024; off <<= 1) {
    int v = (t >= off) ? part[t - off] : 0;
    __syncthreads();
    part[t] += v;
    __syncthreads();
  }
  int run = (t == 0) ? 0 : part[t - 1];
  int* st = starts + pl * (NBIN + 1);
  int* cur = cursor + pl * NBIN;
  for (int i = 0; i < 64; ++i) {
    st[base + i] = run;
    cur[base + i] = run;
    run += c[base + i];
  }
  if (t == 1023) st[NBIN] = run;
}

__global__ __launch_bounds__(256) void k_place(const int* __restrict__ idx,
                                               int* __restrict__ cursor,
                                               int* __restrict__ plist) {
  int e = blockIdx.x * 256 + threadIdx.x;    // 3*BTOT
  int pl = e / BTOT, pt = e - pl * BTOT;
  int pos = atomicAdd(&cursor[pl * NBIN + idx[e]], 1);
  plist[(size_t)pl * BTOT + pos] = pt;
}

// ---------- fc_pos ----------
__global__ __launch_bounds__(256) void k_fcpos(const float* __restrict__ p,
                                               const float* __restrict__ w,
                                               const float* __restrict__ b,
                                               float* __restrict__ netA,
                                               float* __restrict__ poolB) {
  int e = blockIdx.x * 256 + threadIdx.x;
  int pt = e >> 8, col = e & 255;
  float x0 = p[pt * 3 + 0], x1 = p[pt * 3 + 1], x2 = p[pt * 3 + 2];
  float v = b[col] + x0 * w[col] + x1 * w[256 + col] + x2 * w[512 + col];
  if (col < HDIM) netA[(size_t)pt * HDIM + col] = v;
  else            poolB[(size_t)pt * HDIM + (col - HDIM)] = v;
}

// ---------- weight packing into MFMA B-fragment order (bf16 hi/lo) ----------
__global__ __launch_bounds__(256) void k_pack(const float* __restrict__ bw0,
                                              const float* __restrict__ bw1,
                                              const float* __restrict__ bws,
                                              unsigned short* __restrict__ P1H,
                                              unsigned short* __restrict__ P1L,
                                              unsigned short* __restrict__ P2H,
                                              unsigned short* __restrict__ P2L) {
  int t = blockIdx.x * 256 + threadIdx.x;
  if (t >= 5 * 20 * 8 * 64) return;
  int lane = t & 63;
  int r = t >> 6;
  int nt = r & 7; r >>= 3;
  int kb20 = r % 20;
  int l = r / 20;
  int quad = lane >> 4;
  int n = nt * 16 + (lane & 15);
#pragma unroll
  for (int j = 0; j < 8; ++j) {
    if (kb20 < 8) {
      int k = kb20 * 32 + quad * 8 + j;
      float v = bw0[((size_t)l * 256 + k) * 128 + n];
      size_t didx = (((size_t)(l * 8 + kb20) * 8 + nt) * 64 + lane) * 8 + j;
      unsigned short h = f2bf_rtn(v);
      P1H[didx] = h;
      P1L[didx] = f2bf_rtn(v - bf2f(h));
    } else {
      int kb = kb20 - 8;
      int k = kb * 32 + quad * 8 + j;
      float v = (k < 256) ? bws[((size_t)l * 256 + k) * 128 + n]
                          : bw1[((size_t)l * 128 + (k - 256)) * 128 + n];
      size_t didx = (((size_t)(l * 12 + kb) * 8 + nt) * 64 + lane) * 8 + j;
      unsigned short h = f2bf_rtn(v);
      P2H[didx] = h;
      P2L[didx] = f2bf_rtn(v - bf2f(h));
    }
  }
}

// ---------- list-based pooling max: seg[pl][bin][128] = max over bin pts ----
__global__ __launch_bounds__(256) void k_poolmax(const float* __restrict__ net,
                                                 const int* __restrict__ starts,
                                                 const int* __restrict__ plist,
                                                 float* __restrict__ seg) {
  int tid = threadIdx.x;
  int pl = blockIdx.y;
  int bin = blockIdx.x * 2 + (tid >> 7);
  int ch = tid & 127;
  const int* st = starts + pl * (NBIN + 1);
  int s = st[bin], e = st[bin + 1];
  if (s >= e) return;                    // empty bin: never gathered
  const int* pli = plist + (size_t)pl * BTOT;
  float v = -3.4e38f;
  for (int k = s; k < e; ++k) {
    int pid = pli[k];
    v = fmaxf(v, net[(size_t)pid * 128 + ch]);
  }
  seg[((size_t)pl * NBIN + bin) * 128 + ch] = v;
}

// ---------- fused resblock with in-kernel 3-plane gather ----------
// 64 rows/block, 256 threads (4 waves). A-side bf16 hi only; B hi/lo 2-term.
__global__ __launch_bounds__(256) void k_resblock(
    float* __restrict__ netA, const float* __restrict__ segB,
    const int* __restrict__ idx, int mode,
    const unsigned short* __restrict__ P1H, const unsigned short* __restrict__ P1L,
    const unsigned short* __restrict__ P2H, const unsigned short* __restrict__ P2L,
    const float* __restrict__ b0, const float* __restrict__ b1) {
  __shared__ __align__(16) unsigned short xh[64][264];
  __shared__ __align__(16) unsigned short th[64][136];
  int tid = threadIdx.x;
  int rows0 = blockIdx.x * 64;

  // stage A: build x = [netA | pooled] in bf16
#pragma unroll
  for (int i = 0; i < 16; ++i) {
    int f4 = i * 256 + tid;             // [0,4096)
    int row = f4 >> 6;
    int col = (f4 & 63) * 4;
    int grow = rows0 + row;
    float4 f;
    if (col < 128) {
      f = *(const float4*)(netA + (size_t)grow * 128 + col);
    } else {
      int cc = col - 128;
      if (mode == 0) {
        f = *(const float4*)(segB + (size_t)grow * 128 + cc);
      } else {
        int i0 = idx[grow], i1 = idx[BTOT + grow], i2 = idx[2 * BTOT + grow];
        float4 a = *(const float4*)(segB + (size_t)i0 * 128 + cc);
        float4 b4 = *(const float4*)(segB + (size_t)NBIN * 128 + (size_t)i1 * 128 + cc);
        float4 c4 = *(const float4*)(segB + (size_t)2 * NBIN * 128 + (size_t)i2 * 128 + cc);
        f.x = a.x + b4.x + c4.x;
        f.y = a.y + b4.y + c4.y;
        f.z = a.z + b4.z + c4.z;
        f.w = a.w + b4.w + c4.w;
      }
    }
    short4v hv;
    hv[0] = (short)f2bf_rtn(f.x);
    hv[1] = (short)f2bf_rtn(f.y);
    hv[2] = (short)f2bf_rtn(f.z);
    hv[3] = (short)f2bf_rtn(f.w);
    *(short4v*)&xh[row][col] = hv;
  }
  __syncthreads();

  int lane = tid & 63;
  int wv = tid >> 6;
  int cg = wv & 1;                 // 64-col group
  int rh = wv >> 1;                // 32-row half
  int quad = lane >> 4;
  int m0 = rh * 32 + (lane & 15);

  // ---- stage 1: t = relu(x) @ w0 + b0 ----
  floatx4 acc[2][4] = {};
  for (int kb = 0; kb < 8; ++kb) {
    short8 a0 = relu8(*(const short8*)&xh[m0][kb * 32 + quad * 8]);
    short8 a1 = relu8(*(const short8*)&xh[m0 + 16][kb * 32 + quad * 8]);
    const short8* wh = (const short8*)P1H + ((size_t)(kb * 8 + cg * 4) * 64 + lane);
    const short8* wl = (const short8*)P1L + ((size_t)(kb * 8 + cg * 4) * 64 + lane);
#pragma unroll
    for (int nti = 0; nti < 4; ++nti) {
      short8 bh = wh[nti * 64];
      short8 bl = wl[nti * 64];
      acc[0][nti] = __builtin_amdgcn_mfma_f32_16x16x32_bf16(a0, bh, acc[0][nti], 0, 0, 0);
      acc[0][nti] = __builtin_amdgcn_mfma_f32_16x16x32_bf16(a0, bl, acc[0][nti], 0, 0, 0);
      acc[1][nti] = __builtin_amdgcn_mfma_f32_16x16x32_bf16(a1, bh, acc[1][nti], 0, 0, 0);
      acc[1][nti] = __builtin_amdgcn_mfma_f32_16x16x32_bf16(a1, bl, acc[1][nti], 0, 0, 0);
    }
  }
  // epilogue 1: bias + relu -> th (bf16)
#pragma unroll
  for (int rs = 0; rs < 2; ++rs) {
#pragma unroll
    for (int nti = 0; nti < 4; ++nti) {
      int col = cg * 64 + nti * 16 + (lane & 15);
      float bb = b0[col];
#pragma unroll
      for (int r = 0; r < 4; ++r) {
        int row = rh * 32 + rs * 16 + quad * 4 + r;
        float v = fmaxf(acc[rs][nti][r] + bb, 0.0f);
        th[row][col] = f2bf_rtn(v);
      }
    }
  }
  __syncthreads();

  // ---- stage 2: out = x @ ws + relu_t @ w1 + b1 ----
  floatx4 acc2[2][4] = {};
  for (int kb = 0; kb < 12; ++kb) {
    short8 a0, a1;
    if (kb < 8) {
      a0 = *(const short8*)&xh[m0][kb * 32 + quad * 8];
      a1 = *(const short8*)&xh[m0 + 16][kb * 32 + quad * 8];
    } else {
      a0 = *(const short8*)&th[m0][(kb - 8) * 32 + quad * 8];
      a1 = *(const short8*)&th[m0 + 16][(kb - 8) * 32 + quad * 8];
    }
    const short8* wh = (const short8*)P2H + ((size_t)(kb * 8 + cg * 4) * 64 + lane);
    const short8* wl = (const short8*)P2L + ((size_t)(kb * 8 + cg * 4) * 64 + lane);
#pragma unroll
    for (int nti = 0; nti < 4; ++nti) {
      short8 bh = wh[nti * 64];
      short8 bl = wl[nti * 64];
      acc2[0][nti] = __builtin_amdgcn_mfma_f32_16x16x32_bf16(a0, bh, acc2[0][nti], 0, 0, 0);
      acc2[0][nti] = __builtin_amdgcn_mfma_f32_16x16x32_bf16(a0, bl, acc2[0][nti], 0, 0, 0);
      acc2[1][nti] = __builtin_amdgcn_mfma_f32_16x16x32_bf16(a1, bh, acc2[1][nti], 0, 0, 0);
      acc2[1][nti] = __builtin_amdgcn_mfma_f32_16x16x32_bf16(a1, bl, acc2[1][nti], 0, 0, 0);
    }
  }
  // epilogue 2: bias + store fp32 (in-place; block owns rows)
#pragma unroll
  for (int rs = 0; rs < 2; ++rs) {
#pragma unroll
    for (int nti = 0; nti < 4; ++nti) {
      int col = cg * 64 + nti * 16 + (lane & 15);
      float bb = b1[col];
#pragma unroll
      for (int r = 0; r < 4; ++r) {
        int row = rows0 + rh * 32 + rs * 16 + quad * 4 + r;
        netA[(size_t)row * 128 + col] = acc2[rs][nti][r] + bb;
      }
    }
  }
}

// ---------- fc_c ----------
__global__ __launch_bounds__(256) void k_fcc(const float* __restrict__ x,
                                             const float* __restrict__ w,
                                             const float* __restrict__ b,
                                             float* __restrict__ c) {
  __shared__ __align__(16) float xs[16][128];
  int row0 = blockIdx.x * 16;
  int tid = threadIdx.x;
#pragma unroll
  for (int rr = 0; rr < 8; ++rr) {
    int e = rr * 256 + tid;
    int r = e >> 7, cc = e & 127;
    xs[r][cc] = x[(size_t)(row0 + r) * 128 + cc];
  }
  __syncthreads();
  int j = tid & 63;
  int r0 = (tid >> 6) * 4;
  float a0 = 0.f, a1 = 0.f, a2 = 0.f, a3 = 0.f;
  for (int k = 0; k < 128; k += 4) {
    float w_0 = w[(k + 0) * 64 + j];
    float w_1 = w[(k + 1) * 64 + j];
    float w_2 = w[(k + 2) * 64 + j];
    float w_3 = w[(k + 3) * 64 + j];
    float4 x0 = *(const float4*)&xs[r0 + 0][k];
    float4 x1 = *(const float4*)&xs[r0 + 1][k];
    float4 x2 = *(const float4*)&xs[r0 + 2][k];
    float4 x3 = *(const float4*)&xs[r0 + 3][k];
    a0 = fmaf(x0.x, w_0, fmaf(x0.y, w_1, fmaf(x0.z, w_2, fmaf(x0.w, w_3, a0))));
    a1 = fmaf(x1.x, w_0, fmaf(x1.y, w_1, fmaf(x1.z, w_2, fmaf(x1.w, w_3, a1))));
    a2 = fmaf(x2.x, w_0, fmaf(x2.y, w_1, fmaf(x2.z, w_2, fmaf(x2.w, w_3, a2))));
    a3 = fmaf(x3.x, w_0, fmaf(x3.y, w_1, fmaf(x3.z, w_2, fmaf(x3.w, w_3, a3))));
  }
  float bb = b[j];
  c[(size_t)(row0 + r0 + 0) * 64 + j] = a0 + bb;
  c[(size_t)(row0 + r0 + 1) * 64 + j] = a1 + bb;
  c[(size_t)(row0 + r0 + 2) * 64 + j] = a2 + bb;
  c[(size_t)(row0 + r0 + 3) * 64 + j] = a3 + bb;
}

// ---------- fused list-based scatter-mean + transposed output ----------
__global__ __launch_bounds__(256) void k_meanout(const float* __restrict__ c,
                                                 const int* __restrict__ starts,
                                                 const int* __restrict__ plist,
                                                 float* __restrict__ out) {
  __shared__ float tile[64][65];
  int tid = threadIdx.x;
  int pb = blockIdx.y;                 // pl*4 + b
  int pl = pb >> 2;
  int b = pb & 3;
  int bin0 = blockIdx.x * 64;
  int w = tid >> 6, lane = tid & 63;
  const int* st = starts + pl * (NBIN + 1) + b * R2_ + bin0;
  const int* pli = plist + (size_t)pl * BTOT;
  for (int lb = w * 16; lb < w * 16 + 16; ++lb) {
    int s = st[lb], e = st[lb + 1];
    float sum = 0.0f;
    for (int k = s; k < e; ++k) {
      int pid = pli[k];
      sum += c[(size_t)pid * 64 + lane];
    }
    tile[lb][lane] = sum / fmaxf((float)(e - s), 1.0f);
  }
  __syncthreads();
#pragma unroll
  for (int i = 0; i < 16; ++i) {
    int e2 = i * 256 + tid;
    int ch = e2 >> 6, lb = e2 & 63;
    out[((size_t)pb * 64 + ch) * R2_ + bin0 + lb] = tile[lb][ch];
  }
}

extern "C" void kernel_launch(void* const* d_in, const int* in_sizes, int n_in,
                              void* d_out, int out_size, void* d_ws, size_t ws_size,
                              hipStream_t stream) {
  const float* p    = (const float*)d_in[0];
  const float* fcw  = (const float*)d_in[1];
  const float* fcb  = (const float*)d_in[2];
  const float* bw0  = (const float*)d_in[3];
  const float* bb0  = (const float*)d_in[4];
  const float* bw1  = (const float*)d_in[5];
  const float* bb1  = (const float*)d_in[6];
  const float* bws  = (const float*)d_in[7];
  const float* fccw = (const float*)d_in[8];
  const float* fccb = (const float*)d_in[9];
  float* out = (float*)d_out;

  char* ws = (char*)d_ws;
  const size_t SZnet = (size_t)BTOT * 128 * 4;          // 64 MiB
  const size_t P1_LAYER = 8 * 8 * 64 * 8;               // shorts
  const size_t P2_LAYER = 12 * 8 * 64 * 8;              // shorts

  size_t off = 0;
  float* netA = (float*)(ws + off); off += SZnet;
  int*   idx  = (int*)(ws + off);   off += (size_t)3 * BTOT * 4;
  unsigned short* P1H = (unsigned short*)(ws + off); off += 5 * P1_LAYER * 2;
  unsigned short* P1L = (unsigned short*)(ws + off); off += 5 * P1_LAYER * 2;
  unsigned short* P2H = (unsigned short*)(ws + off); off += 5 * P2_LAYER * 2;
  unsigned short* P2L = (unsigned short*)(ws + off); off += 5 * P2_LAYER * 2;
  int* cntb   = (int*)(ws + off); off += (size_t)3 * NBIN * 4;
  int* starts = (int*)(ws + off); off += (size_t)3 * (NBIN + 1) * 4;
  int* cursor = (int*)(ws + off); off += (size_t)3 * NBIN * 4;
  int* plist  = (int*)(ws + off); off += (size_t)3 * BTOT * 4;
  off = (off + 255) & ~(size_t)255;
  float* seg = (float*)(ws + off);  // 3*NBIN*128*4 = 100.7 MiB
  float* poolB = seg;               // fc_pos B-half; dead before first poolmax
  float* cbuf  = seg;               // c features; seg dead after last resblock

  k_idx<<<BTOT / 256, 256, 0, stream>>>(p, idx);
  hipMemsetAsync(cntb, 0, (size_t)3 * NBIN * 4, stream);
  k_count<<<3 * BTOT / 256, 256, 0, stream>>>(idx, cntb);
  k_scan<<<3, 1024, 0, stream>>>(cntb, starts, cursor);
  k_place<<<3 * BTOT / 256, 256, 0, stream>>>(idx, cursor, plist);
  k_pack<<<200, 256, 0, stream>>>(bw0, bw1, bws, P1H, P1L, P2H, P2L);
  k_fcpos<<<BTOT, 256, 0, stream>>>(p, fcw, fcb, netA, poolB);

  for (int blk = 0; blk < 5; ++blk) {
    if (blk > 0) {
      dim3 g(NBIN / 2, 3);
      k_poolmax<<<g, 256, 0, stream>>>(netA, starts, plist, seg);
    }
    k_resblock<<<BTOT / 64, 256, 0, stream>>>(
        netA, seg, idx, (blk > 0) ? 1 : 0,
        P1H + (size_t)blk * P1_LAYER, P1L + (size_t)blk * P1_LAYER,
        P2H + (size_t)blk * P2_LAYER, P2L + (size_t)blk * P2_LAYER,
        bb0 + (size_t)blk * 128, bb1 + (size_t)blk * 128);
  }

  k_fcc<<<BTOT / 16, 256, 0, stream>>>(netA, fccw, fccb, cbuf);

  dim3 gm(R2_ / 64, 12);
  k_meanout<<<gm, 256, 0, stream>>>(cbuf, starts, plist, out);
}

// Round 4
// 1063.515 us; speedup vs baseline: 3.7427x; 1.3170x over previous
//
#include <hip/hip_runtime.h>
#include <cstddef>

static constexpr int BTOT = 131072;     // B*T
static constexpr int RESO_ = 128;
static constexpr int R2_ = RESO_ * RESO_;   // 16384
static constexpr int NBIN = 4 * R2_;        // B*R2 = 65536
static constexpr int HDIM = 128;
static constexpr int CDIM = 64;

typedef __attribute__((ext_vector_type(8))) short short8;
typedef __attribute__((ext_vector_type(4))) short short4v;
typedef __attribute__((ext_vector_type(4))) float floatx4;

// ---------- bf16 helpers ----------
__device__ __forceinline__ unsigned short f2bf_rtn(float f) {
  unsigned u = __float_as_uint(f);
  unsigned r = u + 0x7FFFu + ((u >> 16) & 1u);
  return (unsigned short)(r >> 16);
}
__device__ __forceinline__ float bf2f(unsigned short h) {
  return __uint_as_float(((unsigned)h) << 16);
}
__device__ __forceinline__ short8 relu8(short8 v) {
#pragma unroll
  for (int i = 0; i < 8; ++i) v[i] = (v[i] < (short)0) ? (short)0 : v[i];
  return v;
}

// ---------- bin indices for the 3 planes ----------
__global__ __launch_bounds__(256) void k_idx(const float* __restrict__ p,
                                             int* __restrict__ idx) {
  int pt = blockIdx.x * 256 + threadIdx.x;
  const float DIVC = (float)(1.0 + 0.1 + 1e-5);
  const float HI = (float)(1.0 - 1e-5);
  float x = p[pt * 3 + 0], y = p[pt * 3 + 1], z = p[pt * 3 + 2];
  float nx = fminf(fmaxf(x / DIVC + 0.5f, 0.0f), HI);
  float ny = fminf(fmaxf(y / DIVC + 0.5f, 0.0f), HI);
  float nz = fminf(fmaxf(z / DIVC + 0.5f, 0.0f), HI);
  int ix = (int)(nx * (float)RESO_);
  int iy = (int)(ny * (float)RESO_);
  int iz = (int)(nz * (float)RESO_);
  int off = (pt >> 15) * R2_;
  idx[0 * BTOT + pt] = ix + RESO_ * iz + off; // xz
  idx[1 * BTOT + pt] = ix + RESO_ * iy + off; // xy
  idx[2 * BTOT + pt] = iy + RESO_ * iz + off; // yz
}

// ---------- bin list construction ----------
__global__ __launch_bounds__(256) void k_count(const int* __restrict__ idx,
                                               int* __restrict__ cnt) {
  int e = blockIdx.x * 256 + threadIdx.x;    // 3*BTOT
  int pl = e / BTOT;
  atomicAdd(&cnt[pl * NBIN + idx[e]], 1);
}

__global__ __launch_bounds__(1024) void k_scan(const int* __restrict__ cnt,
                                               int* __restrict__ starts,
                                               int* __restrict__ cursor) {
  __shared__ int part[1024];
  int pl = blockIdx.x;
  int t = threadIdx.x;
  const int* c = cnt + pl * NBIN;
  int base = t * 64;
  int s = 0;
  for (int i = 0; i < 64; ++i) s += c[base + i];
  part[t] = s;
  __syncthreads();
  for (int off = 1; off < 1024; off <<= 1) {
    int v = (t >= off) ? part[t - off] : 0;
    __syncthreads();
    part[t] += v;
    __syncthreads();
  }
  int run = (t == 0) ? 0 : part[t - 1];
  int* st = starts + pl * (NBIN + 1);
  int* cur = cursor + pl * NBIN;
  for (int i = 0; i < 64; ++i) {
    st[base + i] = run;
    cur[base + i] = run;
    run += c[base + i];
  }
  if (t == 1023) st[NBIN] = run;
}

__global__ __launch_bounds__(256) void k_place(const int* __restrict__ idx,
                                               int* __restrict__ cursor,
                                               int* __restrict__ plist) {
  int e = blockIdx.x * 256 + threadIdx.x;    // 3*BTOT
  int pl = e / BTOT, pt = e - pl * BTOT;
  int pos = atomicAdd(&cursor[pl * NBIN + idx[e]], 1);
  plist[(size_t)pl * BTOT + pos] = pt;
}

// ---------- fc_pos -> bf16 netA / poolB ----------
__global__ __launch_bounds__(256) void k_fcpos(const float* __restrict__ p,
                                               const float* __restrict__ w,
                                               const float* __restrict__ b,
                                               unsigned short* __restrict__ netA,
                                               unsigned short* __restrict__ poolB) {
  int e = blockIdx.x * 256 + threadIdx.x;
  int pt = e >> 8, col = e & 255;
  float x0 = p[pt * 3 + 0], x1 = p[pt * 3 + 1], x2 = p[pt * 3 + 2];
  float v = b[col] + x0 * w[col] + x1 * w[256 + col] + x2 * w[512 + col];
  unsigned short h = f2bf_rtn(v);
  if (col < HDIM) netA[(size_t)pt * HDIM + col] = h;
  else            poolB[(size_t)pt * HDIM + (col - HDIM)] = h;
}

// ---------- weight packing into MFMA B-fragment order (bf16 hi/lo) ----------
__global__ __launch_bounds__(256) void k_pack(const float* __restrict__ bw0,
                                              const float* __restrict__ bw1,
                                              const float* __restrict__ bws,
                                              unsigned short* __restrict__ P1H,
                                              unsigned short* __restrict__ P1L,
                                              unsigned short* __restrict__ P2H,
                                              unsigned short* __restrict__ P2L) {
  int t = blockIdx.x * 256 + threadIdx.x;
  if (t >= 5 * 20 * 8 * 64) return;
  int lane = t & 63;
  int r = t >> 6;
  int nt = r & 7; r >>= 3;
  int kb20 = r % 20;
  int l = r / 20;
  int quad = lane >> 4;
  int n = nt * 16 + (lane & 15);
#pragma unroll
  for (int j = 0; j < 8; ++j) {
    if (kb20 < 8) {
      int k = kb20 * 32 + quad * 8 + j;
      float v = bw0[((size_t)l * 256 + k) * 128 + n];
      size_t didx = (((size_t)(l * 8 + kb20) * 8 + nt) * 64 + lane) * 8 + j;
      unsigned short h = f2bf_rtn(v);
      P1H[didx] = h;
      P1L[didx] = f2bf_rtn(v - bf2f(h));
    } else {
      int kb = kb20 - 8;
      int k = kb * 32 + quad * 8 + j;
      float v = (k < 256) ? bws[((size_t)l * 256 + k) * 128 + n]
                          : bw1[((size_t)l * 128 + (k - 256)) * 128 + n];
      size_t didx = (((size_t)(l * 12 + kb) * 8 + nt) * 64 + lane) * 8 + j;
      unsigned short h = f2bf_rtn(v);
      P2H[didx] = h;
      P2L[didx] = f2bf_rtn(v - bf2f(h));
    }
  }
}

// ---------- list-based pooling max (bf16): seg[pl][bin][128] ----------
// 4 bins per 256-block; 64 lanes per bin; lane covers 2 channels (uint load).
__global__ __launch_bounds__(256) void k_poolmax(const unsigned short* __restrict__ net,
                                                 const int* __restrict__ starts,
                                                 const int* __restrict__ plist,
                                                 unsigned short* __restrict__ seg) {
  int tid = threadIdx.x;
  int pl = blockIdx.y;
  int bin = blockIdx.x * 4 + (tid >> 6);
  int lane = tid & 63;
  const int* st = starts + pl * (NBIN + 1);
  int s = st[bin], e = st[bin + 1];
  if (s >= e) return;                    // empty bin: never gathered
  const int* pli = plist + (size_t)pl * BTOT;
  float v0 = -3.4e38f, v1 = -3.4e38f;
  for (int k = s; k < e; ++k) {
    int pid = pli[k];
    unsigned u = *(const unsigned*)(net + (size_t)pid * 128 + lane * 2);
    v0 = fmaxf(v0, bf2f((unsigned short)(u & 0xffffu)));
    v1 = fmaxf(v1, bf2f((unsigned short)(u >> 16)));
  }
  // inputs exact bf16 -> truncation is exact
  unsigned o = (__float_as_uint(v0) >> 16) | (__float_as_uint(v1) & 0xffff0000u);
  *(unsigned*)(seg + ((size_t)pl * NBIN + bin) * 128 + lane * 2) = o;
}

// ---------- fused resblock with in-kernel 3-plane gather (all bf16 I/O) ----
// 64 rows/block, 256 threads (4 waves). A-side bf16; B-side hi/lo 2-term.
__global__ __launch_bounds__(256) void k_resblock(
    unsigned short* __restrict__ netA, const unsigned short* __restrict__ segB,
    const int* __restrict__ idx, int mode,
    const unsigned short* __restrict__ P1H, const unsigned short* __restrict__ P1L,
    const unsigned short* __restrict__ P2H, const unsigned short* __restrict__ P2L,
    const float* __restrict__ b0, const float* __restrict__ b1) {
  __shared__ __align__(16) unsigned short xh[64][264];
  __shared__ __align__(16) unsigned short th[64][136];
  int tid = threadIdx.x;
  int rows0 = blockIdx.x * 64;

  // stage A: x = [netA | pooled] bf16, 8-col groups
#pragma unroll
  for (int i = 0; i < 8; ++i) {
    int g8 = i * 256 + tid;             // [0,2048): 64 rows x 32 groups
    int row = g8 >> 5;
    int col = (g8 & 31) * 8;
    int grow = rows0 + row;
    if (col < 128) {
      *(short8*)&xh[row][col] = *(const short8*)(netA + (size_t)grow * 128 + col);
    } else {
      int cc = col - 128;
      if (mode == 0) {
        *(short8*)&xh[row][col] = *(const short8*)(segB + (size_t)grow * 128 + cc);
      } else {
        int i0 = idx[grow], i1 = idx[BTOT + grow], i2 = idx[2 * BTOT + grow];
        short8 a = *(const short8*)(segB + (size_t)i0 * 128 + cc);
        short8 b8 = *(const short8*)(segB + (size_t)NBIN * 128 + (size_t)i1 * 128 + cc);
        short8 c8 = *(const short8*)(segB + (size_t)2 * NBIN * 128 + (size_t)i2 * 128 + cc);
        short8 hv;
#pragma unroll
        for (int q = 0; q < 8; ++q) {
          float f = bf2f((unsigned short)a[q]) + bf2f((unsigned short)b8[q])
                  + bf2f((unsigned short)c8[q]);
          hv[q] = (short)f2bf_rtn(f);
        }
        *(short8*)&xh[row][col] = hv;
      }
    }
  }
  __syncthreads();

  int lane = tid & 63;
  int wv = tid >> 6;
  int cg = wv & 1;                 // 64-col group
  int rh = wv >> 1;                // 32-row half
  int quad = lane >> 4;
  int m0 = rh * 32 + (lane & 15);

  // ---- stage 1: t = relu(x) @ w0 + b0 ----
  floatx4 acc[2][4] = {};
  for (int kb = 0; kb < 8; ++kb) {
    short8 a0 = relu8(*(const short8*)&xh[m0][kb * 32 + quad * 8]);
    short8 a1 = relu8(*(const short8*)&xh[m0 + 16][kb * 32 + quad * 8]);
    const short8* wh = (const short8*)P1H + ((size_t)(kb * 8 + cg * 4) * 64 + lane);
    const short8* wl = (const short8*)P1L + ((size_t)(kb * 8 + cg * 4) * 64 + lane);
#pragma unroll
    for (int nti = 0; nti < 4; ++nti) {
      short8 bh = wh[nti * 64];
      short8 bl = wl[nti * 64];
      acc[0][nti] = __builtin_amdgcn_mfma_f32_16x16x32_bf16(a0, bh, acc[0][nti], 0, 0, 0);
      acc[0][nti] = __builtin_amdgcn_mfma_f32_16x16x32_bf16(a0, bl, acc[0][nti], 0, 0, 0);
      acc[1][nti] = __builtin_amdgcn_mfma_f32_16x16x32_bf16(a1, bh, acc[1][nti], 0, 0, 0);
      acc[1][nti] = __builtin_amdgcn_mfma_f32_16x16x32_bf16(a1, bl, acc[1][nti], 0, 0, 0);
    }
  }
  // epilogue 1: bias + relu -> th (bf16)
#pragma unroll
  for (int rs = 0; rs < 2; ++rs) {
#pragma unroll
    for (int nti = 0; nti < 4; ++nti) {
      int col = cg * 64 + nti * 16 + (lane & 15);
      float bb = b0[col];
#pragma unroll
      for (int r = 0; r < 4; ++r) {
        int row = rh * 32 + rs * 16 + quad * 4 + r;
        float v = fmaxf(acc[rs][nti][r] + bb, 0.0f);
        th[row][col] = f2bf_rtn(v);
      }
    }
  }
  __syncthreads();

  // ---- stage 2: out = x @ ws + relu_t @ w1 + b1 ----
  floatx4 acc2[2][4] = {};
  for (int kb = 0; kb < 12; ++kb) {
    short8 a0, a1;
    if (kb < 8) {
      a0 = *(const short8*)&xh[m0][kb * 32 + quad * 8];
      a1 = *(const short8*)&xh[m0 + 16][kb * 32 + quad * 8];
    } else {
      a0 = *(const short8*)&th[m0][(kb - 8) * 32 + quad * 8];
      a1 = *(const short8*)&th[m0 + 16][(kb - 8) * 32 + quad * 8];
    }
    const short8* wh = (const short8*)P2H + ((size_t)(kb * 8 + cg * 4) * 64 + lane);
    const short8* wl = (const short8*)P2L + ((size_t)(kb * 8 + cg * 4) * 64 + lane);
#pragma unroll
    for (int nti = 0; nti < 4; ++nti) {
      short8 bh = wh[nti * 64];
      short8 bl = wl[nti * 64];
      acc2[0][nti] = __builtin_amdgcn_mfma_f32_16x16x32_bf16(a0, bh, acc2[0][nti], 0, 0, 0);
      acc2[0][nti] = __builtin_amdgcn_mfma_f32_16x16x32_bf16(a0, bl, acc2[0][nti], 0, 0, 0);
      acc2[1][nti] = __builtin_amdgcn_mfma_f32_16x16x32_bf16(a1, bh, acc2[1][nti], 0, 0, 0);
      acc2[1][nti] = __builtin_amdgcn_mfma_f32_16x16x32_bf16(a1, bl, acc2[1][nti], 0, 0, 0);
    }
  }
  // epilogue 2: bias + bf16 store (in-place; block owns rows)
#pragma unroll
  for (int rs = 0; rs < 2; ++rs) {
#pragma unroll
    for (int nti = 0; nti < 4; ++nti) {
      int col = cg * 64 + nti * 16 + (lane & 15);
      float bb = b1[col];
#pragma unroll
      for (int r = 0; r < 4; ++r) {
        int row = rows0 + rh * 32 + rs * 16 + quad * 4 + r;
        netA[(size_t)row * 128 + col] = f2bf_rtn(acc2[rs][nti][r] + bb);
      }
    }
  }
}

// ---------- fc_c (bf16 in, fp32 out) ----------
__global__ __launch_bounds__(256) void k_fcc(const unsigned short* __restrict__ x,
                                             const float* __restrict__ w,
                                             const float* __restrict__ b,
                                             float* __restrict__ c) {
  __shared__ __align__(16) float xs[16][128];
  int row0 = blockIdx.x * 16;
  int tid = threadIdx.x;
  {
    int r = tid >> 4;
    int c0 = (tid & 15) * 8;
    short8 v = *(const short8*)(x + (size_t)(row0 + r) * 128 + c0);
#pragma unroll
    for (int q = 0; q < 8; ++q) xs[r][c0 + q] = bf2f((unsigned short)v[q]);
  }
  __syncthreads();
  int j = tid & 63;
  int r0 = (tid >> 6) * 4;
  float a0 = 0.f, a1 = 0.f, a2 = 0.f, a3 = 0.f;
  for (int k = 0; k < 128; k += 4) {
    float w_0 = w[(k + 0) * 64 + j];
    float w_1 = w[(k + 1) * 64 + j];
    float w_2 = w[(k + 2) * 64 + j];
    float w_3 = w[(k + 3) * 64 + j];
    float4 x0 = *(const float4*)&xs[r0 + 0][k];
    float4 x1 = *(const float4*)&xs[r0 + 1][k];
    float4 x2 = *(const float4*)&xs[r0 + 2][k];
    float4 x3 = *(const float4*)&xs[r0 + 3][k];
    a0 = fmaf(x0.x, w_0, fmaf(x0.y, w_1, fmaf(x0.z, w_2, fmaf(x0.w, w_3, a0))));
    a1 = fmaf(x1.x, w_0, fmaf(x1.y, w_1, fmaf(x1.z, w_2, fmaf(x1.w, w_3, a1))));
    a2 = fmaf(x2.x, w_0, fmaf(x2.y, w_1, fmaf(x2.z, w_2, fmaf(x2.w, w_3, a2))));
    a3 = fmaf(x3.x, w_0, fmaf(x3.y, w_1, fmaf(x3.z, w_2, fmaf(x3.w, w_3, a3))));
  }
  float bb = b[j];
  c[(size_t)(row0 + r0 + 0) * 64 + j] = a0 + bb;
  c[(size_t)(row0 + r0 + 1) * 64 + j] = a1 + bb;
  c[(size_t)(row0 + r0 + 2) * 64 + j] = a2 + bb;
  c[(size_t)(row0 + r0 + 3) * 64 + j] = a3 + bb;
}

// ---------- fused list-based scatter-mean + transposed output ----------
__global__ __launch_bounds__(256) void k_meanout(const float* __restrict__ c,
                                                 const int* __restrict__ starts,
                                                 const int* __restrict__ plist,
                                                 float* __restrict__ out) {
  __shared__ float tile[64][65];
  int tid = threadIdx.x;
  int pb = blockIdx.y;                 // pl*4 + b
  int pl = pb >> 2;
  int b = pb & 3;
  int bin0 = blockIdx.x * 64;
  int w = tid >> 6, lane = tid & 63;
  const int* st = starts + pl * (NBIN + 1) + b * R2_ + bin0;
  const int* pli = plist + (size_t)pl * BTOT;
  for (int lb = w * 16; lb < w * 16 + 16; ++lb) {
    int s = st[lb], e = st[lb + 1];
    float sum = 0.0f;
    for (int k = s; k < e; ++k) {
      int pid = pli[k];
      sum += c[(size_t)pid * 64 + lane];
    }
    tile[lb][lane] = sum / fmaxf((float)(e - s), 1.0f);
  }
  __syncthreads();
#pragma unroll
  for (int i = 0; i < 16; ++i) {
    int e2 = i * 256 + tid;
    int ch = e2 >> 6, lb = e2 & 63;
    out[((size_t)pb * 64 + ch) * R2_ + bin0 + lb] = tile[lb][ch];
  }
}

extern "C" void kernel_launch(void* const* d_in, const int* in_sizes, int n_in,
                              void* d_out, int out_size, void* d_ws, size_t ws_size,
                              hipStream_t stream) {
  const float* p    = (const float*)d_in[0];
  const float* fcw  = (const float*)d_in[1];
  const float* fcb  = (const float*)d_in[2];
  const float* bw0  = (const float*)d_in[3];
  const float* bb0  = (const float*)d_in[4];
  const float* bw1  = (const float*)d_in[5];
  const float* bb1  = (const float*)d_in[6];
  const float* bws  = (const float*)d_in[7];
  const float* fccw = (const float*)d_in[8];
  const float* fccb = (const float*)d_in[9];
  float* out = (float*)d_out;

  char* ws = (char*)d_ws;
  const size_t P1_LAYER = 8 * 8 * 64 * 8;               // shorts
  const size_t P2_LAYER = 12 * 8 * 64 * 8;              // shorts

  size_t off = 0;
  unsigned short* netA = (unsigned short*)(ws + off); off += (size_t)BTOT * 128 * 2;
  int*   idx  = (int*)(ws + off);   off += (size_t)3 * BTOT * 4;
  unsigned short* P1H = (unsigned short*)(ws + off); off += 5 * P1_LAYER * 2;
  unsigned short* P1L = (unsigned short*)(ws + off); off += 5 * P1_LAYER * 2;
  unsigned short* P2H = (unsigned short*)(ws + off); off += 5 * P2_LAYER * 2;
  unsigned short* P2L = (unsigned short*)(ws + off); off += 5 * P2_LAYER * 2;
  int* cntb   = (int*)(ws + off); off += (size_t)3 * NBIN * 4;
  int* starts = (int*)(ws + off); off += (size_t)3 * (NBIN + 1) * 4;
  int* cursor = (int*)(ws + off); off += (size_t)3 * NBIN * 4;
  int* plist  = (int*)(ws + off); off += (size_t)3 * BTOT * 4;
  off = (off + 255) & ~(size_t)255;
  unsigned short* seg = (unsigned short*)(ws + off); // 3*NBIN*128*2 = 50.3 MiB
  unsigned short* poolB = seg;       // fc_pos B-half; dead before first poolmax
  float* cbuf = (float*)seg;         // c features; seg dead after last resblock

  k_idx<<<BTOT / 256, 256, 0, stream>>>(p, idx);
  hipMemsetAsync(cntb, 0, (size_t)3 * NBIN * 4, stream);
  k_count<<<3 * BTOT / 256, 256, 0, stream>>>(idx, cntb);
  k_scan<<<3, 1024, 0, stream>>>(cntb, starts, cursor);
  k_place<<<3 * BTOT / 256, 256, 0, stream>>>(idx, cursor, plist);
  k_pack<<<200, 256, 0, stream>>>(bw0, bw1, bws, P1H, P1L, P2H, P2L);
  k_fcpos<<<BTOT, 256, 0, stream>>>(p, fcw, fcb, netA, poolB);

  for (int blk = 0; blk < 5; ++blk) {
    if (blk > 0) {
      dim3 g(NBIN / 4, 3);
      k_poolmax<<<g, 256, 0, stream>>>(netA, starts, plist, seg);
    }
    k_resblock<<<BTOT / 64, 256, 0, stream>>>(
        netA, seg, idx, (blk > 0) ? 1 : 0,
        P1H + (size_t)blk * P1_LAYER, P1L + (size_t)blk * P1_LAYER,
        P2H + (size_t)blk * P2_LAYER, P2L + (size_t)blk * P2_LAYER,
        bb0 + (size_t)blk * 128, bb1 + (size_t)blk * 128);
  }

  k_fcc<<<BTOT / 16, 256, 0, stream>>>(netA, fccw, fccb, cbuf);

  dim3 gm(R2_ / 64, 12);
  k_meanout<<<gm, 256, 0, stream>>>(cbuf, starts, plist, out);
}

// Round 5
// 842.727 us; speedup vs baseline: 4.7233x; 1.2620x over previous
//
#include <hip/hip_runtime.h>
#include <hip/hip_fp16.h>
#include <cstddef>

static constexpr int BTOT = 131072;     // B*T
static constexpr int RESO_ = 128;
static constexpr int R2_ = RESO_ * RESO_;   // 16384
static constexpr int NBIN = 4 * R2_;        // B*R2 = 65536
static constexpr int HDIM = 128;
static constexpr int CDIM = 64;

typedef __attribute__((ext_vector_type(8))) short short8;
typedef _Float16 half8 __attribute__((ext_vector_type(8)));
typedef __attribute__((ext_vector_type(4))) float floatx4;

__device__ __forceinline__ unsigned short f2h(float f) {
  return __half_as_ushort(__float2half(f));   // RTN
}
__device__ __forceinline__ float h2f(unsigned short h) {
  return __half2float(__ushort_as_half(h));
}
// relu on packed f16: sign bit = bit15, so int16 compare works (+0.0 = 0x0000)
__device__ __forceinline__ short8 relu8(short8 v) {
#pragma unroll
  for (int i = 0; i < 8; ++i) v[i] = (v[i] < (short)0) ? (short)0 : v[i];
  return v;
}

// ---------- bin indices for the 3 planes ----------
__global__ __launch_bounds__(256) void k_idx(const float* __restrict__ p,
                                             int* __restrict__ idx) {
  int pt = blockIdx.x * 256 + threadIdx.x;
  const float DIVC = (float)(1.0 + 0.1 + 1e-5);
  const float HI = (float)(1.0 - 1e-5);
  float x = p[pt * 3 + 0], y = p[pt * 3 + 1], z = p[pt * 3 + 2];
  float nx = fminf(fmaxf(x / DIVC + 0.5f, 0.0f), HI);
  float ny = fminf(fmaxf(y / DIVC + 0.5f, 0.0f), HI);
  float nz = fminf(fmaxf(z / DIVC + 0.5f, 0.0f), HI);
  int ix = (int)(nx * (float)RESO_);
  int iy = (int)(ny * (float)RESO_);
  int iz = (int)(nz * (float)RESO_);
  int off = (pt >> 15) * R2_;
  idx[0 * BTOT + pt] = ix + RESO_ * iz + off; // xz
  idx[1 * BTOT + pt] = ix + RESO_ * iy + off; // xy
  idx[2 * BTOT + pt] = iy + RESO_ * iz + off; // yz
}

// ---------- bin list construction ----------
__global__ __launch_bounds__(256) void k_count(const int* __restrict__ idx,
                                               int* __restrict__ cnt) {
  int e = blockIdx.x * 256 + threadIdx.x;    // 3*BTOT
  int pl = e / BTOT;
  atomicAdd(&cnt[pl * NBIN + idx[e]], 1);
}

__global__ __launch_bounds__(1024) void k_scan(const int* __restrict__ cnt,
                                               int* __restrict__ starts,
                                               int* __restrict__ cursor) {
  __shared__ int part[1024];
  int pl = blockIdx.x;
  int t = threadIdx.x;
  const int* c = cnt + pl * NBIN;
  int base = t * 64;
  int s = 0;
  for (int i = 0; i < 64; ++i) s += c[base + i];
  part[t] = s;
  __syncthreads();
  for (int off = 1; off < 1024; off <<= 1) {
    int v = (t >= off) ? part[t - off] : 0;
    __syncthreads();
    part[t] += v;
    __syncthreads();
  }
  int run = (t == 0) ? 0 : part[t - 1];
  int* st = starts + pl * (NBIN + 1);
  int* cur = cursor + pl * NBIN;
  for (int i = 0; i < 64; ++i) {
    st[base + i] = run;
    cur[base + i] = run;
    run += c[base + i];
  }
  if (t == 1023) st[NBIN] = run;
}

__global__ __launch_bounds__(256) void k_place(const int* __restrict__ idx,
                                               int* __restrict__ cursor,
                                               int* __restrict__ plist) {
  int e = blockIdx.x * 256 + threadIdx.x;    // 3*BTOT
  int pl = e / BTOT, pt = e - pl * BTOT;
  int pos = atomicAdd(&cursor[pl * NBIN + idx[e]], 1);
  plist[(size_t)pl * BTOT + pos] = pt;
}

// ---------- fc_pos -> f16 netA / poolB ----------
__global__ __launch_bounds__(256) void k_fcpos(const float* __restrict__ p,
                                               const float* __restrict__ w,
                                               const float* __restrict__ b,
                                               unsigned short* __restrict__ netA,
                                               unsigned short* __restrict__ poolB) {
  int e = blockIdx.x * 256 + threadIdx.x;
  int pt = e >> 8, col = e & 255;
  float x0 = p[pt * 3 + 0], x1 = p[pt * 3 + 1], x2 = p[pt * 3 + 2];
  float v = b[col] + x0 * w[col] + x1 * w[256 + col] + x2 * w[512 + col];
  unsigned short h = f2h(v);
  if (col < HDIM) netA[(size_t)pt * HDIM + col] = h;
  else            poolB[(size_t)pt * HDIM + (col - HDIM)] = h;
}

// ---------- weight packing into MFMA B-fragment order (single f16) ----------
// P1: per layer, w0 [256x128]: frag(kb,nt): value = w0[kb*32+(lane>>4)*8+j][nt*16+(lane&15)]
// P2: per layer, concat_k(ws [256x128], w1 [128x128]): kb in [0,12)
__global__ __launch_bounds__(256) void k_pack(const float* __restrict__ bw0,
                                              const float* __restrict__ bw1,
                                              const float* __restrict__ bws,
                                              unsigned short* __restrict__ P1,
                                              unsigned short* __restrict__ P2) {
  int t = blockIdx.x * 256 + threadIdx.x;
  if (t >= 5 * 20 * 8 * 64) return;
  int lane = t & 63;
  int r = t >> 6;
  int nt = r & 7; r >>= 3;
  int kb20 = r % 20;
  int l = r / 20;
  int quad = lane >> 4;
  int n = nt * 16 + (lane & 15);
#pragma unroll
  for (int j = 0; j < 8; ++j) {
    if (kb20 < 8) {
      int k = kb20 * 32 + quad * 8 + j;
      float v = bw0[((size_t)l * 256 + k) * 128 + n];
      size_t didx = (((size_t)(l * 8 + kb20) * 8 + nt) * 64 + lane) * 8 + j;
      P1[didx] = f2h(v);
    } else {
      int kb = kb20 - 8;
      int k = kb * 32 + quad * 8 + j;
      float v = (k < 256) ? bws[((size_t)l * 256 + k) * 128 + n]
                          : bw1[((size_t)l * 128 + (k - 256)) * 128 + n];
      size_t didx = (((size_t)(l * 12 + kb) * 8 + nt) * 64 + lane) * 8 + j;
      P2[didx] = f2h(v);
    }
  }
}

// ---------- list-based pooling max (f16): seg[pl][bin][128] ----------
__global__ __launch_bounds__(256) void k_poolmax(const unsigned short* __restrict__ net,
                                                 const int* __restrict__ starts,
                                                 const int* __restrict__ plist,
                                                 unsigned short* __restrict__ seg) {
  int tid = threadIdx.x;
  int pl = blockIdx.y;
  int bin = blockIdx.x * 4 + (tid >> 6);
  int lane = tid & 63;
  const int* st = starts + pl * (NBIN + 1);
  int s = st[bin], e = st[bin + 1];
  if (s >= e) return;                    // empty bin: never gathered
  const int* pli = plist + (size_t)pl * BTOT;
  float v0 = -3.4e38f, v1 = -3.4e38f;
  for (int k = s; k < e; ++k) {
    int pid = pli[k];
    unsigned u = *(const unsigned*)(net + (size_t)pid * 128 + lane * 2);
    v0 = fmaxf(v0, h2f((unsigned short)(u & 0xffffu)));
    v1 = fmaxf(v1, h2f((unsigned short)(u >> 16)));
  }
  unsigned o = (unsigned)f2h(v0) | ((unsigned)f2h(v1) << 16);  // exact (values are f16)
  *(unsigned*)(seg + ((size_t)pl * NBIN + bin) * 128 + lane * 2) = o;
}

// ---------- fused resblock with in-kernel 3-plane gather (all f16) ----------
// 32 rows/block, 256 threads (4 waves): cg = col-half (64), rh = row-half (16).
// LDS 25 KB -> 6 blocks/CU for gather-latency hiding.
__global__ __launch_bounds__(256, 6) void k_resblock(
    unsigned short* __restrict__ netA, const unsigned short* __restrict__ segB,
    const int* __restrict__ idx, int mode,
    const unsigned short* __restrict__ P1, const unsigned short* __restrict__ P2,
    const float* __restrict__ b0, const float* __restrict__ b1) {
  __shared__ __align__(16) unsigned short xh[32][264];
  __shared__ __align__(16) unsigned short th[32][136];
  int tid = threadIdx.x;
  int rows0 = blockIdx.x * 32;

  // stage A: x = [netA | pooled] f16, 8-col groups
#pragma unroll
  for (int i = 0; i < 4; ++i) {
    int g8 = i * 256 + tid;             // [0,1024): 32 rows x 32 groups
    int row = g8 >> 5;
    int col = (g8 & 31) * 8;
    int grow = rows0 + row;
    if (col < 128) {
      *(short8*)&xh[row][col] = *(const short8*)(netA + (size_t)grow * 128 + col);
    } else {
      int cc = col - 128;
      if (mode == 0) {
        *(short8*)&xh[row][col] = *(const short8*)(segB + (size_t)grow * 128 + cc);
      } else {
        int i0 = idx[grow], i1 = idx[BTOT + grow], i2 = idx[2 * BTOT + grow];
        short8 a = *(const short8*)(segB + (size_t)i0 * 128 + cc);
        short8 b8 = *(const short8*)(segB + (size_t)NBIN * 128 + (size_t)i1 * 128 + cc);
        short8 c8 = *(const short8*)(segB + (size_t)2 * NBIN * 128 + (size_t)i2 * 128 + cc);
        short8 hv;
#pragma unroll
        for (int q = 0; q < 8; ++q) {
          float f = h2f((unsigned short)a[q]) + h2f((unsigned short)b8[q])
                  + h2f((unsigned short)c8[q]);
          hv[q] = (short)f2h(f);
        }
        *(short8*)&xh[row][col] = hv;
      }
    }
  }
  __syncthreads();

  int lane = tid & 63;
  int wv = tid >> 6;
  int cg = wv & 1;                 // 64-col group
  int rh = wv >> 1;                // 16-row half
  int quad = lane >> 4;
  int m0 = rh * 16 + (lane & 15);

  // ---- stage 1: t = relu(x) @ w0 + b0 ----
  floatx4 acc[4] = {};
  for (int kb = 0; kb < 8; ++kb) {
    short8 as = relu8(*(const short8*)&xh[m0][kb * 32 + quad * 8]);
    half8 a0 = *(half8*)&as;
    const short8* wf = (const short8*)P1 + ((size_t)(kb * 8 + cg * 4) * 64 + lane);
#pragma unroll
    for (int nti = 0; nti < 4; ++nti) {
      short8 bs = wf[nti * 64];
      acc[nti] = __builtin_amdgcn_mfma_f32_16x16x32_f16(a0, *(half8*)&bs, acc[nti], 0, 0, 0);
    }
  }
  // epilogue 1: bias + relu -> th (f16)
#pragma unroll
  for (int nti = 0; nti < 4; ++nti) {
    int col = cg * 64 + nti * 16 + (lane & 15);
    float bb = b0[col];
#pragma unroll
    for (int r = 0; r < 4; ++r) {
      int row = rh * 16 + quad * 4 + r;
      th[row][col] = f2h(fmaxf(acc[nti][r] + bb, 0.0f));
    }
  }
  __syncthreads();

  // ---- stage 2: out = x @ ws + relu_t @ w1 + b1 ----
  floatx4 acc2[4] = {};
  for (int kb = 0; kb < 12; ++kb) {
    short8 as = (kb < 8) ? *(const short8*)&xh[m0][kb * 32 + quad * 8]
                         : *(const short8*)&th[m0][(kb - 8) * 32 + quad * 8];
    half8 a0 = *(half8*)&as;
    const short8* wf = (const short8*)P2 + ((size_t)(kb * 8 + cg * 4) * 64 + lane);
#pragma unroll
    for (int nti = 0; nti < 4; ++nti) {
      short8 bs = wf[nti * 64];
      acc2[nti] = __builtin_amdgcn_mfma_f32_16x16x32_f16(a0, *(half8*)&bs, acc2[nti], 0, 0, 0);
    }
  }
  // epilogue 2: bias + f16 store (in-place; block owns rows)
#pragma unroll
  for (int nti = 0; nti < 4; ++nti) {
    int col = cg * 64 + nti * 16 + (lane & 15);
    float bb = b1[col];
#pragma unroll
    for (int r = 0; r < 4; ++r) {
      int row = rows0 + rh * 16 + quad * 4 + r;
      netA[(size_t)row * 128 + col] = f2h(acc2[nti][r] + bb);
    }
  }
}

// ---------- fc_c (f16 in, f16 out) ----------
__global__ __launch_bounds__(256) void k_fcc(const unsigned short* __restrict__ x,
                                             const float* __restrict__ w,
                                             const float* __restrict__ b,
                                             unsigned short* __restrict__ c) {
  __shared__ __align__(16) float xs[16][128];
  int row0 = blockIdx.x * 16;
  int tid = threadIdx.x;
  {
    int r = tid >> 4;
    int c0 = (tid & 15) * 8;
    short8 v = *(const short8*)(x + (size_t)(row0 + r) * 128 + c0);
#pragma unroll
    for (int q = 0; q < 8; ++q) xs[r][c0 + q] = h2f((unsigned short)v[q]);
  }
  __syncthreads();
  int j = tid & 63;
  int r0 = (tid >> 6) * 4;
  float a0 = 0.f, a1 = 0.f, a2 = 0.f, a3 = 0.f;
  for (int k = 0; k < 128; k += 4) {
    float w_0 = w[(k + 0) * 64 + j];
    float w_1 = w[(k + 1) * 64 + j];
    float w_2 = w[(k + 2) * 64 + j];
    float w_3 = w[(k + 3) * 64 + j];
    float4 x0 = *(const float4*)&xs[r0 + 0][k];
    float4 x1 = *(const float4*)&xs[r0 + 1][k];
    float4 x2 = *(const float4*)&xs[r0 + 2][k];
    float4 x3 = *(const float4*)&xs[r0 + 3][k];
    a0 = fmaf(x0.x, w_0, fmaf(x0.y, w_1, fmaf(x0.z, w_2, fmaf(x0.w, w_3, a0))));
    a1 = fmaf(x1.x, w_0, fmaf(x1.y, w_1, fmaf(x1.z, w_2, fmaf(x1.w, w_3, a1))));
    a2 = fmaf(x2.x, w_0, fmaf(x2.y, w_1, fmaf(x2.z, w_2, fmaf(x2.w, w_3, a2))));
    a3 = fmaf(x3.x, w_0, fmaf(x3.y, w_1, fmaf(x3.z, w_2, fmaf(x3.w, w_3, a3))));
  }
  float bb = b[j];
  c[(size_t)(row0 + r0 + 0) * 64 + j] = f2h(a0 + bb);
  c[(size_t)(row0 + r0 + 1) * 64 + j] = f2h(a1 + bb);
  c[(size_t)(row0 + r0 + 2) * 64 + j] = f2h(a2 + bb);
  c[(size_t)(row0 + r0 + 3) * 64 + j] = f2h(a3 + bb);
}

// ---------- fused list-based scatter-mean + transposed output ----------
__global__ __launch_bounds__(256) void k_meanout(const unsigned short* __restrict__ c,
                                                 const int* __restrict__ starts,
                                                 const int* __restrict__ plist,
                                                 float* __restrict__ out) {
  __shared__ float tile[64][65];
  int tid = threadIdx.x;
  int pb = blockIdx.y;                 // pl*4 + b
  int pl = pb >> 2;
  int b = pb & 3;
  int bin0 = blockIdx.x * 64;
  int w = tid >> 6, lane = tid & 63;
  const int* st = starts + pl * (NBIN + 1) + b * R2_ + bin0;
  const int* pli = plist + (size_t)pl * BTOT;
  for (int lb = w * 16; lb < w * 16 + 16; ++lb) {
    int s = st[lb], e = st[lb + 1];
    float sum = 0.0f;
    for (int k = s; k < e; ++k) {
      int pid = pli[k];
      sum += h2f(c[(size_t)pid * 64 + lane]);
    }
    tile[lb][lane] = sum / fmaxf((float)(e - s), 1.0f);
  }
  __syncthreads();
#pragma unroll
  for (int i = 0; i < 16; ++i) {
    int e2 = i * 256 + tid;
    int ch = e2 >> 6, lb = e2 & 63;
    out[((size_t)pb * 64 + ch) * R2_ + bin0 + lb] = tile[lb][ch];
  }
}

extern "C" void kernel_launch(void* const* d_in, const int* in_sizes, int n_in,
                              void* d_out, int out_size, void* d_ws, size_t ws_size,
                              hipStream_t stream) {
  const float* p    = (const float*)d_in[0];
  const float* fcw  = (const float*)d_in[1];
  const float* fcb  = (const float*)d_in[2];
  const float* bw0  = (const float*)d_in[3];
  const float* bb0  = (const float*)d_in[4];
  const float* bw1  = (const float*)d_in[5];
  const float* bb1  = (const float*)d_in[6];
  const float* bws  = (const float*)d_in[7];
  const float* fccw = (const float*)d_in[8];
  const float* fccb = (const float*)d_in[9];
  float* out = (float*)d_out;

  char* ws = (char*)d_ws;
  const size_t P1_LAYER = 8 * 8 * 64 * 8;               // shorts
  const size_t P2_LAYER = 12 * 8 * 64 * 8;              // shorts

  size_t off = 0;
  unsigned short* netA = (unsigned short*)(ws + off); off += (size_t)BTOT * 128 * 2;
  int*   idx  = (int*)(ws + off);   off += (size_t)3 * BTOT * 4;
  unsigned short* P1 = (unsigned short*)(ws + off); off += 5 * P1_LAYER * 2;
  unsigned short* P2 = (unsigned short*)(ws + off); off += 5 * P2_LAYER * 2;
  int* cntb   = (int*)(ws + off); off += (size_t)3 * NBIN * 4;
  int* starts = (int*)(ws + off); off += (size_t)3 * (NBIN + 1) * 4;
  int* cursor = (int*)(ws + off); off += (size_t)3 * NBIN * 4;
  int* plist  = (int*)(ws + off); off += (size_t)3 * BTOT * 4;
  off = (off + 255) & ~(size_t)255;
  unsigned short* seg = (unsigned short*)(ws + off); // 3*NBIN*128*2 = 50.3 MiB
  unsigned short* poolB = seg;       // fc_pos B-half; dead before first poolmax
  unsigned short* cbuf = seg;        // c features; seg dead after last resblock

  k_idx<<<BTOT / 256, 256, 0, stream>>>(p, idx);
  hipMemsetAsync(cntb, 0, (size_t)3 * NBIN * 4, stream);
  k_count<<<3 * BTOT / 256, 256, 0, stream>>>(idx, cntb);
  k_scan<<<3, 1024, 0, stream>>>(cntb, starts, cursor);
  k_place<<<3 * BTOT / 256, 256, 0, stream>>>(idx, cursor, plist);
  k_pack<<<200, 256, 0, stream>>>(bw0, bw1, bws, P1, P2);
  k_fcpos<<<BTOT, 256, 0, stream>>>(p, fcw, fcb, netA, poolB);

  for (int blk = 0; blk < 5; ++blk) {
    if (blk > 0) {
      dim3 g(NBIN / 4, 3);
      k_poolmax<<<g, 256, 0, stream>>>(netA, starts, plist, seg);
    }
    k_resblock<<<BTOT / 32, 256, 0, stream>>>(
        netA, seg, idx, (blk > 0) ? 1 : 0,
        P1 + (size_t)blk * P1_LAYER, P2 + (size_t)blk * P2_LAYER,
        bb0 + (size_t)blk * 128, bb1 + (size_t)blk * 128);
  }

  k_fcc<<<BTOT / 16, 256, 0, stream>>>(netA, fccw, fccb, cbuf);

  dim3 gm(R2_ / 64, 12);
  k_meanout<<<gm, 256, 0, stream>>>(cbuf, starts, plist, out);
}

// Round 6
// 742.466 us; speedup vs baseline: 5.3611x; 1.1350x over previous
//
#include <hip/hip_runtime.h>
#include <hip/hip_fp16.h>
#include <cstddef>

static constexpr int BTOT = 131072;     // B*T
static constexpr int RESO_ = 128;
static constexpr int R2_ = RESO_ * RESO_;   // 16384
static constexpr int NBIN = 4 * R2_;        // B*R2 = 65536
static constexpr int HDIM = 128;
static constexpr int CDIM = 64;

typedef __attribute__((ext_vector_type(8))) short short8;
typedef _Float16 half8 __attribute__((ext_vector_type(8)));
typedef __attribute__((ext_vector_type(4))) float floatx4;

__device__ __forceinline__ unsigned short f2h(float f) {
  return __half_as_ushort(__float2half(f));   // RTN
}
__device__ __forceinline__ float h2f(unsigned short h) {
  return __half2float(__ushort_as_half(h));
}
// relu on packed f16: sign bit = bit15, so int16 compare works (+0.0 = 0x0000)
__device__ __forceinline__ short8 relu8(short8 v) {
#pragma unroll
  for (int i = 0; i < 8; ++i) v[i] = (v[i] < (short)0) ? (short)0 : v[i];
  return v;
}

// ---------- bin indices for the 3 planes ----------
__global__ __launch_bounds__(256) void k_idx(const float* __restrict__ p,
                                             int* __restrict__ idx) {
  int pt = blockIdx.x * 256 + threadIdx.x;
  const float DIVC = (float)(1.0 + 0.1 + 1e-5);
  const float HI = (float)(1.0 - 1e-5);
  float x = p[pt * 3 + 0], y = p[pt * 3 + 1], z = p[pt * 3 + 2];
  float nx = fminf(fmaxf(x / DIVC + 0.5f, 0.0f), HI);
  float ny = fminf(fmaxf(y / DIVC + 0.5f, 0.0f), HI);
  float nz = fminf(fmaxf(z / DIVC + 0.5f, 0.0f), HI);
  int ix = (int)(nx * (float)RESO_);
  int iy = (int)(ny * (float)RESO_);
  int iz = (int)(nz * (float)RESO_);
  int off = (pt >> 15) * R2_;
  idx[0 * BTOT + pt] = ix + RESO_ * iz + off; // xz
  idx[1 * BTOT + pt] = ix + RESO_ * iy + off; // xy
  idx[2 * BTOT + pt] = iy + RESO_ * iz + off; // yz
}

// ---------- bin list construction ----------
__global__ __launch_bounds__(256) void k_count(const int* __restrict__ idx,
                                               int* __restrict__ cnt) {
  int e = blockIdx.x * 256 + threadIdx.x;    // 3*BTOT
  int pl = e / BTOT;
  atomicAdd(&cnt[pl * NBIN + idx[e]], 1);
}

__global__ __launch_bounds__(1024) void k_scan(const int* __restrict__ cnt,
                                               int* __restrict__ starts,
                                               int* __restrict__ cursor) {
  __shared__ int part[1024];
  int pl = blockIdx.x;
  int t = threadIdx.x;
  const int* c = cnt + pl * NBIN;
  int base = t * 64;
  int s = 0;
  for (int i = 0; i < 64; ++i) s += c[base + i];
  part[t] = s;
  __syncthreads();
  for (int off = 1; off < 1024; off <<= 1) {
    int v = (t >= off) ? part[t - off] : 0;
    __syncthreads();
    part[t] += v;
    __syncthreads();
  }
  int run = (t == 0) ? 0 : part[t - 1];
  int* st = starts + pl * (NBIN + 1);
  int* cur = cursor + pl * NBIN;
  for (int i = 0; i < 64; ++i) {
    st[base + i] = run;
    cur[base + i] = run;
    run += c[base + i];
  }
  if (t == 1023) st[NBIN] = run;
}

__global__ __launch_bounds__(256) void k_place(const int* __restrict__ idx,
                                               int* __restrict__ cursor,
                                               int* __restrict__ plist) {
  int e = blockIdx.x * 256 + threadIdx.x;    // 3*BTOT
  int pl = e / BTOT, pt = e - pl * BTOT;
  int pos = atomicAdd(&cursor[pl * NBIN + idx[e]], 1);
  plist[(size_t)pl * BTOT + pos] = pt;
}

// ---------- fc_pos -> f16 netA / poolB ----------
__global__ __launch_bounds__(256) void k_fcpos(const float* __restrict__ p,
                                               const float* __restrict__ w,
                                               const float* __restrict__ b,
                                               unsigned short* __restrict__ netA,
                                               unsigned short* __restrict__ poolB) {
  int e = blockIdx.x * 256 + threadIdx.x;
  int pt = e >> 8, col = e & 255;
  float x0 = p[pt * 3 + 0], x1 = p[pt * 3 + 1], x2 = p[pt * 3 + 2];
  float v = b[col] + x0 * w[col] + x1 * w[256 + col] + x2 * w[512 + col];
  unsigned short h = f2h(v);
  if (col < HDIM) netA[(size_t)pt * HDIM + col] = h;
  else            poolB[(size_t)pt * HDIM + (col - HDIM)] = h;
}

// ---------- weight packing into MFMA B-fragment order (single f16) ----------
__global__ __launch_bounds__(256) void k_pack(const float* __restrict__ bw0,
                                              const float* __restrict__ bw1,
                                              const float* __restrict__ bws,
                                              unsigned short* __restrict__ P1,
                                              unsigned short* __restrict__ P2) {
  int t = blockIdx.x * 256 + threadIdx.x;
  if (t >= 5 * 20 * 8 * 64) return;
  int lane = t & 63;
  int r = t >> 6;
  int nt = r & 7; r >>= 3;
  int kb20 = r % 20;
  int l = r / 20;
  int quad = lane >> 4;
  int n = nt * 16 + (lane & 15);
#pragma unroll
  for (int j = 0; j < 8; ++j) {
    if (kb20 < 8) {
      int k = kb20 * 32 + quad * 8 + j;
      float v = bw0[((size_t)l * 256 + k) * 128 + n];
      size_t didx = (((size_t)(l * 8 + kb20) * 8 + nt) * 64 + lane) * 8 + j;
      P1[didx] = f2h(v);
    } else {
      int kb = kb20 - 8;
      int k = kb * 32 + quad * 8 + j;
      float v = (k < 256) ? bws[((size_t)l * 256 + k) * 128 + n]
                          : bw1[((size_t)l * 128 + (k - 256)) * 128 + n];
      size_t didx = (((size_t)(l * 12 + kb) * 8 + nt) * 64 + lane) * 8 + j;
      P2[didx] = f2h(v);
    }
  }
}

// ---------- fc_c weight packing: P3[(kb*4+nt)*64+lane][j] ----------
__global__ __launch_bounds__(256) void k_packc(const float* __restrict__ fccw,
                                               unsigned short* __restrict__ P3) {
  int t = blockIdx.x * 256 + threadIdx.x;    // 4 blocks: 16 frags x 64 lanes
  if (t >= 16 * 64) return;
  int lane = t & 63;
  int fr = t >> 6;
  int nt = fr & 3, kb = fr >> 2;
  int quad = lane >> 4;
  int n = nt * 16 + (lane & 15);
#pragma unroll
  for (int j = 0; j < 8; ++j) {
    int k = kb * 32 + quad * 8 + j;
    P3[((size_t)fr * 64 + lane) * 8 + j] = f2h(fccw[(size_t)k * 64 + n]);
  }
}

// ---------- list-based pooling max (f16): seg[pl][bin][128] ----------
__global__ __launch_bounds__(256) void k_poolmax(const unsigned short* __restrict__ net,
                                                 const int* __restrict__ starts,
                                                 const int* __restrict__ plist,
                                                 unsigned short* __restrict__ seg) {
  int tid = threadIdx.x;
  int pl = blockIdx.y;
  int bin = blockIdx.x * 4 + (tid >> 6);
  int lane = tid & 63;
  const int* st = starts + pl * (NBIN + 1);
  int s = st[bin], e = st[bin + 1];
  if (s >= e) return;                    // empty bin: never gathered
  const int* pli = plist + (size_t)pl * BTOT;
  float v0 = -3.4e38f, v1 = -3.4e38f;
  for (int k = s; k < e; ++k) {
    int pid = pli[k];
    unsigned u = *(const unsigned*)(net + (size_t)pid * 128 + lane * 2);
    v0 = fmaxf(v0, h2f((unsigned short)(u & 0xffffu)));
    v1 = fmaxf(v1, h2f((unsigned short)(u >> 16)));
  }
  unsigned o = (unsigned)f2h(v0) | ((unsigned)f2h(v1) << 16);  // exact (values are f16)
  *(unsigned*)(seg + ((size_t)pl * NBIN + bin) * 128 + lane * 2) = o;
}

// ---------- fused resblock with in-kernel 3-plane gather (all f16) ----------
// 32 rows/block, 4 waves = col quarters; each wave 32 rows x 32 cols
// (2 A-frags x 2 B-frags per kb) -> B-fragment L2 traffic halved vs 16x64.
__global__ __launch_bounds__(256, 6) void k_resblock(
    unsigned short* __restrict__ netA, const unsigned short* __restrict__ segB,
    const int* __restrict__ idx, int mode,
    const unsigned short* __restrict__ P1, const unsigned short* __restrict__ P2,
    const float* __restrict__ b0, const float* __restrict__ b1) {
  __shared__ __align__(16) unsigned short xh[32][264];
  __shared__ __align__(16) unsigned short th[32][136];
  int tid = threadIdx.x;
  int rows0 = blockIdx.x * 32;

  // stage A: x = [netA | pooled] f16, 8-col groups
#pragma unroll
  for (int i = 0; i < 4; ++i) {
    int g8 = i * 256 + tid;             // [0,1024): 32 rows x 32 groups
    int row = g8 >> 5;
    int col = (g8 & 31) * 8;
    int grow = rows0 + row;
    if (col < 128) {
      *(short8*)&xh[row][col] = *(const short8*)(netA + (size_t)grow * 128 + col);
    } else {
      int cc = col - 128;
      if (mode == 0) {
        *(short8*)&xh[row][col] = *(const short8*)(segB + (size_t)grow * 128 + cc);
      } else {
        int i0 = idx[grow], i1 = idx[BTOT + grow], i2 = idx[2 * BTOT + grow];
        short8 a = *(const short8*)(segB + (size_t)i0 * 128 + cc);
        short8 b8 = *(const short8*)(segB + (size_t)NBIN * 128 + (size_t)i1 * 128 + cc);
        short8 c8 = *(const short8*)(segB + (size_t)2 * NBIN * 128 + (size_t)i2 * 128 + cc);
        short8 hv;
#pragma unroll
        for (int q = 0; q < 8; ++q) {
          float f = h2f((unsigned short)a[q]) + h2f((unsigned short)b8[q])
                  + h2f((unsigned short)c8[q]);
          hv[q] = (short)f2h(f);
        }
        *(short8*)&xh[row][col] = hv;
      }
    }
  }
  __syncthreads();

  int lane = tid & 63;
  int cg = tid >> 6;               // col quarter [0,4)
  int quad = lane >> 4;
  int m0 = lane & 15;

  // ---- stage 1: t = relu(x) @ w0 + b0 ----
  floatx4 acc[2][2] = {};
  for (int kb = 0; kb < 8; ++kb) {
    short8 as0 = relu8(*(const short8*)&xh[m0][kb * 32 + quad * 8]);
    short8 as1 = relu8(*(const short8*)&xh[m0 + 16][kb * 32 + quad * 8]);
    half8 a0 = *(half8*)&as0;
    half8 a1 = *(half8*)&as1;
    const short8* wf = (const short8*)P1 + ((size_t)(kb * 8 + cg * 2) * 64 + lane);
#pragma unroll
    for (int nti = 0; nti < 2; ++nti) {
      short8 bs = wf[nti * 64];
      half8 bw = *(half8*)&bs;
      acc[0][nti] = __builtin_amdgcn_mfma_f32_16x16x32_f16(a0, bw, acc[0][nti], 0, 0, 0);
      acc[1][nti] = __builtin_amdgcn_mfma_f32_16x16x32_f16(a1, bw, acc[1][nti], 0, 0, 0);
    }
  }
  // epilogue 1: bias + relu -> th (f16)
#pragma unroll
  for (int rs = 0; rs < 2; ++rs) {
#pragma unroll
    for (int nti = 0; nti < 2; ++nti) {
      int col = cg * 32 + nti * 16 + (lane & 15);
      float bb = b0[col];
#pragma unroll
      for (int r = 0; r < 4; ++r) {
        int row = rs * 16 + quad * 4 + r;
        th[row][col] = f2h(fmaxf(acc[rs][nti][r] + bb, 0.0f));
      }
    }
  }
  __syncthreads();

  // ---- stage 2: out = x @ ws + relu_t @ w1 + b1 ----
  floatx4 acc2[2][2] = {};
  for (int kb = 0; kb < 12; ++kb) {
    short8 as0, as1;
    if (kb < 8) {
      as0 = *(const short8*)&xh[m0][kb * 32 + quad * 8];
      as1 = *(const short8*)&xh[m0 + 16][kb * 32 + quad * 8];
    } else {
      as0 = *(const short8*)&th[m0][(kb - 8) * 32 + quad * 8];
      as1 = *(const short8*)&th[m0 + 16][(kb - 8) * 32 + quad * 8];
    }
    half8 a0 = *(half8*)&as0;
    half8 a1 = *(half8*)&as1;
    const short8* wf = (const short8*)P2 + ((size_t)(kb * 8 + cg * 2) * 64 + lane);
#pragma unroll
    for (int nti = 0; nti < 2; ++nti) {
      short8 bs = wf[nti * 64];
      half8 bw = *(half8*)&bs;
      acc2[0][nti] = __builtin_amdgcn_mfma_f32_16x16x32_f16(a0, bw, acc2[0][nti], 0, 0, 0);
      acc2[1][nti] = __builtin_amdgcn_mfma_f32_16x16x32_f16(a1, bw, acc2[1][nti], 0, 0, 0);
    }
  }
  // epilogue 2: bias + f16 store (in-place; block owns rows)
#pragma unroll
  for (int rs = 0; rs < 2; ++rs) {
#pragma unroll
    for (int nti = 0; nti < 2; ++nti) {
      int col = cg * 32 + nti * 16 + (lane & 15);
      float bb = b1[col];
#pragma unroll
      for (int r = 0; r < 4; ++r) {
        int row = rows0 + rs * 16 + quad * 4 + r;
        netA[(size_t)row * 128 + col] = f2h(acc2[rs][nti][r] + bb);
      }
    }
  }
}

// ---------- fc_c via MFMA (f16 in, f16 out): 32 rows/block, wave = 16 cols ----
__global__ __launch_bounds__(256) void k_fcc(const unsigned short* __restrict__ x,
                                             const unsigned short* __restrict__ P3,
                                             const float* __restrict__ b,
                                             unsigned short* __restrict__ c) {
  __shared__ __align__(16) unsigned short xc[32][136];
  int tid = threadIdx.x;
  int rows0 = blockIdx.x * 32;
#pragma unroll
  for (int i = 0; i < 2; ++i) {
    int g8 = i * 256 + tid;             // 32 rows x 16 groups
    int row = g8 >> 4;
    int col = (g8 & 15) * 8;
    *(short8*)&xc[row][col] = *(const short8*)(x + (size_t)(rows0 + row) * 128 + col);
  }
  __syncthreads();
  int lane = tid & 63;
  int nt = tid >> 6;                    // col group of 16
  int quad = lane >> 4;
  int m0 = lane & 15;
  floatx4 acc[2] = {};
  for (int kb = 0; kb < 4; ++kb) {
    short8 as0 = *(const short8*)&xc[m0][kb * 32 + quad * 8];
    short8 as1 = *(const short8*)&xc[m0 + 16][kb * 32 + quad * 8];
    short8 bs = *((const short8*)P3 + ((size_t)(kb * 4 + nt) * 64 + lane));
    half8 bw = *(half8*)&bs;
    acc[0] = __builtin_amdgcn_mfma_f32_16x16x32_f16(*(half8*)&as0, bw, acc[0], 0, 0, 0);
    acc[1] = __builtin_amdgcn_mfma_f32_16x16x32_f16(*(half8*)&as1, bw, acc[1], 0, 0, 0);
  }
  int col = nt * 16 + (lane & 15);
  float bb = b[col];
#pragma unroll
  for (int rs = 0; rs < 2; ++rs) {
#pragma unroll
    for (int r = 0; r < 4; ++r) {
      int row = rows0 + rs * 16 + quad * 4 + r;
      c[(size_t)row * 64 + col] = f2h(acc[rs][r] + bb);
    }
  }
}

// ---------- fused list-based scatter-mean + transposed output ----------
__global__ __launch_bounds__(256) void k_meanout(const unsigned short* __restrict__ c,
                                                 const int* __restrict__ starts,
                                                 const int* __restrict__ plist,
                                                 float* __restrict__ out) {
  __shared__ float tile[64][65];
  int tid = threadIdx.x;
  int pb = blockIdx.y;                 // pl*4 + b
  int pl = pb >> 2;
  int b = pb & 3;
  int bin0 = blockIdx.x * 64;
  int w = tid >> 6, lane = tid & 63;
  const int* st = starts + pl * (NBIN + 1) + b * R2_ + bin0;
  const int* pli = plist + (size_t)pl * BTOT;
  for (int lb = w * 16; lb < w * 16 + 16; ++lb) {
    int s = st[lb], e = st[lb + 1];
    float sum = 0.0f;
    for (int k = s; k < e; ++k) {
      int pid = pli[k];
      sum += h2f(c[(size_t)pid * 64 + lane]);
    }
    tile[lb][lane] = sum / fmaxf((float)(e - s), 1.0f);
  }
  __syncthreads();
#pragma unroll
  for (int i = 0; i < 16; ++i) {
    int e2 = i * 256 + tid;
    int ch = e2 >> 6, lb = e2 & 63;
    out[((size_t)pb * 64 + ch) * R2_ + bin0 + lb] = tile[lb][ch];
  }
}

extern "C" void kernel_launch(void* const* d_in, const int* in_sizes, int n_in,
                              void* d_out, int out_size, void* d_ws, size_t ws_size,
                              hipStream_t stream) {
  const float* p    = (const float*)d_in[0];
  const float* fcw  = (const float*)d_in[1];
  const float* fcb  = (const float*)d_in[2];
  const float* bw0  = (const float*)d_in[3];
  const float* bb0  = (const float*)d_in[4];
  const float* bw1  = (const float*)d_in[5];
  const float* bb1  = (const float*)d_in[6];
  const float* bws  = (const float*)d_in[7];
  const float* fccw = (const float*)d_in[8];
  const float* fccb = (const float*)d_in[9];
  float* out = (float*)d_out;

  char* ws = (char*)d_ws;
  const size_t P1_LAYER = 8 * 8 * 64 * 8;               // shorts
  const size_t P2_LAYER = 12 * 8 * 64 * 8;              // shorts

  size_t off = 0;
  unsigned short* netA = (unsigned short*)(ws + off); off += (size_t)BTOT * 128 * 2;
  int*   idx  = (int*)(ws + off);   off += (size_t)3 * BTOT * 4;
  unsigned short* P1 = (unsigned short*)(ws + off); off += 5 * P1_LAYER * 2;
  unsigned short* P2 = (unsigned short*)(ws + off); off += 5 * P2_LAYER * 2;
  unsigned short* P3 = (unsigned short*)(ws + off); off += (size_t)16 * 64 * 8 * 2;
  int* cntb   = (int*)(ws + off); off += (size_t)3 * NBIN * 4;
  int* starts = (int*)(ws + off); off += (size_t)3 * (NBIN + 1) * 4;
  int* cursor = (int*)(ws + off); off += (size_t)3 * NBIN * 4;
  int* plist  = (int*)(ws + off); off += (size_t)3 * BTOT * 4;
  off = (off + 255) & ~(size_t)255;
  unsigned short* seg = (unsigned short*)(ws + off); // 3*NBIN*128*2 = 50.3 MiB
  unsigned short* poolB = seg;       // fc_pos B-half; dead before first poolmax
  unsigned short* cbuf = seg;        // c features; seg dead after last resblock

  k_idx<<<BTOT / 256, 256, 0, stream>>>(p, idx);
  hipMemsetAsync(cntb, 0, (size_t)3 * NBIN * 4, stream);
  k_count<<<3 * BTOT / 256, 256, 0, stream>>>(idx, cntb);
  k_scan<<<3, 1024, 0, stream>>>(cntb, starts, cursor);
  k_place<<<3 * BTOT / 256, 256, 0, stream>>>(idx, cursor, plist);
  k_pack<<<200, 256, 0, stream>>>(bw0, bw1, bws, P1, P2);
  k_packc<<<4, 256, 0, stream>>>(fccw, P3);
  k_fcpos<<<BTOT, 256, 0, stream>>>(p, fcw, fcb, netA, poolB);

  for (int blk = 0; blk < 5; ++blk) {
    if (blk > 0) {
      dim3 g(NBIN / 4, 3);
      k_poolmax<<<g, 256, 0, stream>>>(netA, starts, plist, seg);
    }
    k_resblock<<<BTOT / 32, 256, 0, stream>>>(
        netA, seg, idx, (blk > 0) ? 1 : 0,
        P1 + (size_t)blk * P1_LAYER, P2 + (size_t)blk * P2_LAYER,
        bb0 + (size_t)blk * 128, bb1 + (size_t)blk * 128);
  }

  k_fcc<<<BTOT / 32, 256, 0, stream>>>(netA, P3, fccb, cbuf);

  dim3 gm(R2_ / 64, 12);
  k_meanout<<<gm, 256, 0, stream>>>(cbuf, starts, plist, out);
}

// Round 7
// 670.464 us; speedup vs baseline: 5.9369x; 1.1074x over previous
//
#include <hip/hip_runtime.h>
#include <hip/hip_fp16.h>
#include <cstddef>

static constexpr int BTOT = 131072;     // B*T
static constexpr int RESO_ = 128;
static constexpr int R2_ = RESO_ * RESO_;   // 16384
static constexpr int NBIN = 4 * R2_;        // B*R2 = 65536
static constexpr int HDIM = 128;
static constexpr int CDIM = 64;

typedef __attribute__((ext_vector_type(8))) short short8;
typedef _Float16 half8 __attribute__((ext_vector_type(8)));
typedef __attribute__((ext_vector_type(4))) float floatx4;

__device__ __forceinline__ unsigned short f2h(float f) {
  return __half_as_ushort(__float2half(f));   // RTN
}
__device__ __forceinline__ float h2f(unsigned short h) {
  return __half2float(__ushort_as_half(h));
}
// relu on packed f16: sign bit = bit15, so int16 compare works (+0.0 = 0x0000)
__device__ __forceinline__ short8 relu8(short8 v) {
#pragma unroll
  for (int i = 0; i < 8; ++i) v[i] = (v[i] < (short)0) ? (short)0 : v[i];
  return v;
}

// ---------- bin indices for the 3 planes ----------
__global__ __launch_bounds__(256) void k_idx(const float* __restrict__ p,
                                             int* __restrict__ idx) {
  int pt = blockIdx.x * 256 + threadIdx.x;
  const float DIVC = (float)(1.0 + 0.1 + 1e-5);
  const float HI = (float)(1.0 - 1e-5);
  float x = p[pt * 3 + 0], y = p[pt * 3 + 1], z = p[pt * 3 + 2];
  float nx = fminf(fmaxf(x / DIVC + 0.5f, 0.0f), HI);
  float ny = fminf(fmaxf(y / DIVC + 0.5f, 0.0f), HI);
  float nz = fminf(fmaxf(z / DIVC + 0.5f, 0.0f), HI);
  int ix = (int)(nx * (float)RESO_);
  int iy = (int)(ny * (float)RESO_);
  int iz = (int)(nz * (float)RESO_);
  int off = (pt >> 15) * R2_;
  idx[0 * BTOT + pt] = ix + RESO_ * iz + off; // xz
  idx[1 * BTOT + pt] = ix + RESO_ * iy + off; // xy
  idx[2 * BTOT + pt] = iy + RESO_ * iz + off; // yz
}

// ---------- bin list construction ----------
__global__ __launch_bounds__(256) void k_count(const int* __restrict__ idx,
                                               int* __restrict__ cnt) {
  int e = blockIdx.x * 256 + threadIdx.x;    // 3*BTOT
  int pl = e / BTOT;
  atomicAdd(&cnt[pl * NBIN + idx[e]], 1);
}

__global__ __launch_bounds__(1024) void k_scan(const int* __restrict__ cnt,
                                               int* __restrict__ starts,
                                               int* __restrict__ cursor) {
  __shared__ int part[1024];
  int pl = blockIdx.x;
  int t = threadIdx.x;
  const int* c = cnt + pl * NBIN;
  int base = t * 64;
  int s = 0;
  for (int i = 0; i < 64; ++i) s += c[base + i];
  part[t] = s;
  __syncthreads();
  for (int off = 1; off < 1024; off <<= 1) {
    int v = (t >= off) ? part[t - off] : 0;
    __syncthreads();
    part[t] += v;
    __syncthreads();
  }
  int run = (t == 0) ? 0 : part[t - 1];
  int* st = starts + pl * (NBIN + 1);
  int* cur = cursor + pl * NBIN;
  for (int i = 0; i < 64; ++i) {
    st[base + i] = run;
    cur[base + i] = run;
    run += c[base + i];
  }
  if (t == 1023) st[NBIN] = run;
}

__global__ __launch_bounds__(256) void k_place(const int* __restrict__ idx,
                                               int* __restrict__ cursor,
                                               int* __restrict__ plist) {
  int e = blockIdx.x * 256 + threadIdx.x;    // 3*BTOT
  int pl = e / BTOT, pt = e - pl * BTOT;
  int pos = atomicAdd(&cursor[pl * NBIN + idx[e]], 1);
  plist[(size_t)pl * BTOT + pos] = pt;
}

// ---------- fc_pos -> f16 netA / poolB ----------
__global__ __launch_bounds__(256) void k_fcpos(const float* __restrict__ p,
                                               const float* __restrict__ w,
                                               const float* __restrict__ b,
                                               unsigned short* __restrict__ netA,
                                               unsigned short* __restrict__ poolB) {
  int e = blockIdx.x * 256 + threadIdx.x;
  int pt = e >> 8, col = e & 255;
  float x0 = p[pt * 3 + 0], x1 = p[pt * 3 + 1], x2 = p[pt * 3 + 2];
  float v = b[col] + x0 * w[col] + x1 * w[256 + col] + x2 * w[512 + col];
  unsigned short h = f2h(v);
  if (col < HDIM) netA[(size_t)pt * HDIM + col] = h;
  else            poolB[(size_t)pt * HDIM + (col - HDIM)] = h;
}

// ---------- weight packing into MFMA B-fragment order (single f16) ----------
__global__ __launch_bounds__(256) void k_pack(const float* __restrict__ bw0,
                                              const float* __restrict__ bw1,
                                              const float* __restrict__ bws,
                                              unsigned short* __restrict__ P1,
                                              unsigned short* __restrict__ P2) {
  int t = blockIdx.x * 256 + threadIdx.x;
  if (t >= 5 * 20 * 8 * 64) return;
  int lane = t & 63;
  int r = t >> 6;
  int nt = r & 7; r >>= 3;
  int kb20 = r % 20;
  int l = r / 20;
  int quad = lane >> 4;
  int n = nt * 16 + (lane & 15);
#pragma unroll
  for (int j = 0; j < 8; ++j) {
    if (kb20 < 8) {
      int k = kb20 * 32 + quad * 8 + j;
      float v = bw0[((size_t)l * 256 + k) * 128 + n];
      size_t didx = (((size_t)(l * 8 + kb20) * 8 + nt) * 64 + lane) * 8 + j;
      P1[didx] = f2h(v);
    } else {
      int kb = kb20 - 8;
      int k = kb * 32 + quad * 8 + j;
      float v = (k < 256) ? bws[((size_t)l * 256 + k) * 128 + n]
                          : bw1[((size_t)l * 128 + (k - 256)) * 128 + n];
      size_t didx = (((size_t)(l * 12 + kb) * 8 + nt) * 64 + lane) * 8 + j;
      P2[didx] = f2h(v);
    }
  }
}

// ---------- fc_c weight packing: P3[(kb*4+nt)*64+lane][j] ----------
__global__ __launch_bounds__(256) void k_packc(const float* __restrict__ fccw,
                                               unsigned short* __restrict__ P3) {
  int t = blockIdx.x * 256 + threadIdx.x;    // 16 frags x 64 lanes
  if (t >= 16 * 64) return;
  int lane = t & 63;
  int fr = t >> 6;
  int nt = fr & 3, kb = fr >> 2;
  int quad = lane >> 4;
  int n = nt * 16 + (lane & 15);
#pragma unroll
  for (int j = 0; j < 8; ++j) {
    int k = kb * 32 + quad * 8 + j;
    P3[((size_t)fr * 64 + lane) * 8 + j] = f2h(fccw[(size_t)k * 64 + n]);
  }
}

// ---------- list-based pooling max (f16), 4 bins/wave interleaved ----------
// grid (NBIN/16, 3); block 256 = 4 waves x 4 bins. Lane covers 2 channels.
__global__ __launch_bounds__(256) void k_poolmax(const unsigned short* __restrict__ net,
                                                 const int* __restrict__ starts,
                                                 const int* __restrict__ plist,
                                                 unsigned short* __restrict__ seg) {
  int tid = threadIdx.x;
  int pl = blockIdx.y;
  int wv = tid >> 6, lane = tid & 63;
  int bin0 = blockIdx.x * 16 + wv * 4;
  const int* st = starts + pl * (NBIN + 1) + bin0;
  int sa[5];
#pragma unroll
  for (int i = 0; i < 5; ++i) sa[i] = st[i];
  const int* pli = plist + (size_t)pl * BTOT;
  float v0[4], v1[4];
#pragma unroll
  for (int i = 0; i < 4; ++i) { v0[i] = -3.4e38f; v1[i] = -3.4e38f; }
  int lmax = 0;
#pragma unroll
  for (int i = 0; i < 4; ++i) lmax = max(lmax, sa[i + 1] - sa[i]);
  for (int k = 0; k < lmax; ++k) {
#pragma unroll
    for (int i = 0; i < 4; ++i) {         // 4 independent load chains in flight
      int t = sa[i] + k;
      int kk = max(min(t, sa[i + 1] - 1), 0);
      int pid = pli[kk];
      unsigned u = *(const unsigned*)(net + (size_t)pid * 128 + lane * 2);
      if (t < sa[i + 1]) {
        v0[i] = fmaxf(v0[i], h2f((unsigned short)(u & 0xffffu)));
        v1[i] = fmaxf(v1[i], h2f((unsigned short)(u >> 16)));
      }
    }
  }
#pragma unroll
  for (int i = 0; i < 4; ++i) {
    if (sa[i + 1] > sa[i]) {               // empty bins never gathered
      unsigned o = (unsigned)f2h(v0[i]) | ((unsigned)f2h(v1[i]) << 16);
      *(unsigned*)(seg + ((size_t)pl * NBIN + bin0 + i) * 128 + lane * 2) = o;
    }
  }
}

// ---------- fused resblock with in-kernel 3-plane gather (all f16) ----------
// 32 rows/block, 4 waves = col quarters; each wave 32 rows x 32 cols.
// If cOut != nullptr: additionally computes c = net @ fc_c + bc (fused fc_c).
__global__ __launch_bounds__(256, 6) void k_resblock(
    unsigned short* __restrict__ netA, const unsigned short* __restrict__ segB,
    const int* __restrict__ idx, int mode,
    const unsigned short* __restrict__ P1, const unsigned short* __restrict__ P2,
    const float* __restrict__ b0, const float* __restrict__ b1,
    const unsigned short* __restrict__ P3, const float* __restrict__ bc,
    unsigned short* __restrict__ cOut) {
  __shared__ __align__(16) unsigned short xh[32][264];
  __shared__ __align__(16) unsigned short th[32][136];
  int tid = threadIdx.x;
  int rows0 = blockIdx.x * 32;

  // stage A: x = [netA | pooled] f16, 8-col groups
#pragma unroll
  for (int i = 0; i < 4; ++i) {
    int g8 = i * 256 + tid;             // [0,1024): 32 rows x 32 groups
    int row = g8 >> 5;
    int col = (g8 & 31) * 8;
    int grow = rows0 + row;
    if (col < 128) {
      *(short8*)&xh[row][col] = *(const short8*)(netA + (size_t)grow * 128 + col);
    } else {
      int cc = col - 128;
      if (mode == 0) {
        *(short8*)&xh[row][col] = *(const short8*)(segB + (size_t)grow * 128 + cc);
      } else {
        int i0 = idx[grow], i1 = idx[BTOT + grow], i2 = idx[2 * BTOT + grow];
        short8 a = *(const short8*)(segB + (size_t)i0 * 128 + cc);
        short8 b8 = *(const short8*)(segB + (size_t)NBIN * 128 + (size_t)i1 * 128 + cc);
        short8 c8 = *(const short8*)(segB + (size_t)2 * NBIN * 128 + (size_t)i2 * 128 + cc);
        short8 hv;
#pragma unroll
        for (int q = 0; q < 8; ++q) {
          float f = h2f((unsigned short)a[q]) + h2f((unsigned short)b8[q])
                  + h2f((unsigned short)c8[q]);
          hv[q] = (short)f2h(f);
        }
        *(short8*)&xh[row][col] = hv;
      }
    }
  }
  __syncthreads();

  int lane = tid & 63;
  int cg = tid >> 6;               // col quarter [0,4)
  int quad = lane >> 4;
  int m0 = lane & 15;

  // ---- stage 1: t = relu(x) @ w0 + b0 ----
  floatx4 acc[2][2] = {};
  for (int kb = 0; kb < 8; ++kb) {
    short8 as0 = relu8(*(const short8*)&xh[m0][kb * 32 + quad * 8]);
    short8 as1 = relu8(*(const short8*)&xh[m0 + 16][kb * 32 + quad * 8]);
    half8 a0 = *(half8*)&as0;
    half8 a1 = *(half8*)&as1;
    const short8* wf = (const short8*)P1 + ((size_t)(kb * 8 + cg * 2) * 64 + lane);
#pragma unroll
    for (int nti = 0; nti < 2; ++nti) {
      short8 bs = wf[nti * 64];
      half8 bw = *(half8*)&bs;
      acc[0][nti] = __builtin_amdgcn_mfma_f32_16x16x32_f16(a0, bw, acc[0][nti], 0, 0, 0);
      acc[1][nti] = __builtin_amdgcn_mfma_f32_16x16x32_f16(a1, bw, acc[1][nti], 0, 0, 0);
    }
  }
  // epilogue 1: bias + relu -> th (f16)
#pragma unroll
  for (int rs = 0; rs < 2; ++rs) {
#pragma unroll
    for (int nti = 0; nti < 2; ++nti) {
      int col = cg * 32 + nti * 16 + (lane & 15);
      float bb = b0[col];
#pragma unroll
      for (int r = 0; r < 4; ++r) {
        int row = rs * 16 + quad * 4 + r;
        th[row][col] = f2h(fmaxf(acc[rs][nti][r] + bb, 0.0f));
      }
    }
  }
  __syncthreads();

  // ---- stage 2: out = x @ ws + relu_t @ w1 + b1 ----
  floatx4 acc2[2][2] = {};
  for (int kb = 0; kb < 12; ++kb) {
    short8 as0, as1;
    if (kb < 8) {
      as0 = *(const short8*)&xh[m0][kb * 32 + quad * 8];
      as1 = *(const short8*)&xh[m0 + 16][kb * 32 + quad * 8];
    } else {
      as0 = *(const short8*)&th[m0][(kb - 8) * 32 + quad * 8];
      as1 = *(const short8*)&th[m0 + 16][(kb - 8) * 32 + quad * 8];
    }
    half8 a0 = *(half8*)&as0;
    half8 a1 = *(half8*)&as1;
    const short8* wf = (const short8*)P2 + ((size_t)(kb * 8 + cg * 2) * 64 + lane);
#pragma unroll
    for (int nti = 0; nti < 2; ++nti) {
      short8 bs = wf[nti * 64];
      half8 bw = *(half8*)&bs;
      acc2[0][nti] = __builtin_amdgcn_mfma_f32_16x16x32_f16(a0, bw, acc2[0][nti], 0, 0, 0);
      acc2[1][nti] = __builtin_amdgcn_mfma_f32_16x16x32_f16(a1, bw, acc2[1][nti], 0, 0, 0);
    }
  }

  if (!cOut) {
    // epilogue 2: bias + f16 store (in-place; block owns rows)
#pragma unroll
    for (int rs = 0; rs < 2; ++rs) {
#pragma unroll
      for (int nti = 0; nti < 2; ++nti) {
        int col = cg * 32 + nti * 16 + (lane & 15);
        float bb = b1[col];
#pragma unroll
        for (int r = 0; r < 4; ++r) {
          int row = rows0 + rs * 16 + quad * 4 + r;
          netA[(size_t)row * 128 + col] = f2h(acc2[rs][nti][r] + bb);
        }
      }
    }
  } else {
    // fused fc_c: round-trip net through xh, then 8 MFMAs per wave
    __syncthreads();                     // all waves done reading xh/th
#pragma unroll
    for (int rs = 0; rs < 2; ++rs) {
#pragma unroll
      for (int nti = 0; nti < 2; ++nti) {
        int col = cg * 32 + nti * 16 + (lane & 15);
        float bb = b1[col];
#pragma unroll
        for (int r = 0; r < 4; ++r) {
          int row = rs * 16 + quad * 4 + r;
          xh[row][col] = f2h(acc2[rs][nti][r] + bb);
        }
      }
    }
    __syncthreads();
    floatx4 acc3[2] = {};
    for (int kb = 0; kb < 4; ++kb) {
      short8 as0 = *(const short8*)&xh[m0][kb * 32 + quad * 8];
      short8 as1 = *(const short8*)&xh[m0 + 16][kb * 32 + quad * 8];
      short8 bs = *((const short8*)P3 + ((size_t)(kb * 4 + cg) * 64 + lane));
      half8 bw = *(half8*)&bs;
      acc3[0] = __builtin_amdgcn_mfma_f32_16x16x32_f16(*(half8*)&as0, bw, acc3[0], 0, 0, 0);
      acc3[1] = __builtin_amdgcn_mfma_f32_16x16x32_f16(*(half8*)&as1, bw, acc3[1], 0, 0, 0);
    }
    int col = cg * 16 + (lane & 15);
    float bb = bc[col];
#pragma unroll
    for (int rs = 0; rs < 2; ++rs) {
#pragma unroll
      for (int r = 0; r < 4; ++r) {
        int row = rows0 + rs * 16 + quad * 4 + r;
        cOut[(size_t)row * 64 + col] = f2h(acc3[rs][r] + bb);
      }
    }
  }
}

// ---------- fused list-based scatter-mean + transposed output ----------
// 4 bins per wave interleaved for load ILP.
__global__ __launch_bounds__(256) void k_meanout(const unsigned short* __restrict__ c,
                                                 const int* __restrict__ starts,
                                                 const int* __restrict__ plist,
                                                 float* __restrict__ out) {
  __shared__ float tile[64][65];
  int tid = threadIdx.x;
  int pb = blockIdx.y;                 // pl*4 + b
  int pl = pb >> 2;
  int b = pb & 3;
  int bin0 = blockIdx.x * 64;
  int w = tid >> 6, lane = tid & 63;
  const int* st = starts + pl * (NBIN + 1) + b * R2_ + bin0 + w * 16;
  const int* pli = plist + (size_t)pl * BTOT;
  for (int grp = 0; grp < 4; ++grp) {
    int sa[5];
#pragma unroll
    for (int i = 0; i < 5; ++i) sa[i] = st[grp * 4 + i];
    float sum[4] = {0.f, 0.f, 0.f, 0.f};
    int lmax = 0;
#pragma unroll
    for (int i = 0; i < 4; ++i) lmax = max(lmax, sa[i + 1] - sa[i]);
    for (int k = 0; k < lmax; ++k) {
#pragma unroll
      for (int i = 0; i < 4; ++i) {
        int t = sa[i] + k;
        int kk = max(min(t, sa[i + 1] - 1), 0);
        int pid = pli[kk];
        float v = h2f(c[(size_t)pid * 64 + lane]);
        if (t < sa[i + 1]) sum[i] += v;
      }
    }
#pragma unroll
    for (int i = 0; i < 4; ++i) {
      int lb = w * 16 + grp * 4 + i;
      tile[lb][lane] = sum[i] / fmaxf((float)(sa[i + 1] - sa[i]), 1.0f);
    }
  }
  __syncthreads();
#pragma unroll
  for (int i = 0; i < 16; ++i) {
    int e2 = i * 256 + tid;
    int ch = e2 >> 6, lb = e2 & 63;
    out[((size_t)pb * 64 + ch) * R2_ + bin0 + lb] = tile[lb][ch];
  }
}

extern "C" void kernel_launch(void* const* d_in, const int* in_sizes, int n_in,
                              void* d_out, int out_size, void* d_ws, size_t ws_size,
                              hipStream_t stream) {
  const float* p    = (const float*)d_in[0];
  const float* fcw  = (const float*)d_in[1];
  const float* fcb  = (const float*)d_in[2];
  const float* bw0  = (const float*)d_in[3];
  const float* bb0  = (const float*)d_in[4];
  const float* bw1  = (const float*)d_in[5];
  const float* bb1  = (const float*)d_in[6];
  const float* bws  = (const float*)d_in[7];
  const float* fccw = (const float*)d_in[8];
  const float* fccb = (const float*)d_in[9];
  float* out = (float*)d_out;

  char* ws = (char*)d_ws;
  const size_t P1_LAYER = 8 * 8 * 64 * 8;               // shorts
  const size_t P2_LAYER = 12 * 8 * 64 * 8;              // shorts

  size_t off = 0;
  unsigned short* netA = (unsigned short*)(ws + off); off += (size_t)BTOT * 128 * 2;
  unsigned short* cbuf = (unsigned short*)(ws + off); off += (size_t)BTOT * 64 * 2;
  int*   idx  = (int*)(ws + off);   off += (size_t)3 * BTOT * 4;
  unsigned short* P1 = (unsigned short*)(ws + off); off += 5 * P1_LAYER * 2;
  unsigned short* P2 = (unsigned short*)(ws + off); off += 5 * P2_LAYER * 2;
  unsigned short* P3 = (unsigned short*)(ws + off); off += (size_t)16 * 64 * 8 * 2;
  int* cntb   = (int*)(ws + off); off += (size_t)3 * NBIN * 4;
  int* starts = (int*)(ws + off); off += (size_t)3 * (NBIN + 1) * 4;
  int* cursor = (int*)(ws + off); off += (size_t)3 * NBIN * 4;
  int* plist  = (int*)(ws + off); off += (size_t)3 * BTOT * 4;
  off = (off + 255) & ~(size_t)255;
  unsigned short* seg = (unsigned short*)(ws + off); // 3*NBIN*128*2 = 50.3 MiB
  unsigned short* poolB = seg;       // fc_pos B-half; dead before first poolmax

  k_idx<<<BTOT / 256, 256, 0, stream>>>(p, idx);
  hipMemsetAsync(cntb, 0, (size_t)3 * NBIN * 4, stream);
  k_count<<<3 * BTOT / 256, 256, 0, stream>>>(idx, cntb);
  k_scan<<<3, 1024, 0, stream>>>(cntb, starts, cursor);
  k_place<<<3 * BTOT / 256, 256, 0, stream>>>(idx, cursor, plist);
  k_pack<<<200, 256, 0, stream>>>(bw0, bw1, bws, P1, P2);
  k_packc<<<4, 256, 0, stream>>>(fccw, P3);
  k_fcpos<<<BTOT, 256, 0, stream>>>(p, fcw, fcb, netA, poolB);

  for (int blk = 0; blk < 5; ++blk) {
    if (blk > 0) {
      dim3 g(NBIN / 16, 3);
      k_poolmax<<<g, 256, 0, stream>>>(netA, starts, plist, seg);
    }
    k_resblock<<<BTOT / 32, 256, 0, stream>>>(
        netA, seg, idx, (blk > 0) ? 1 : 0,
        P1 + (size_t)blk * P1_LAYER, P2 + (size_t)blk * P2_LAYER,
        bb0 + (size_t)blk * 128, bb1 + (size_t)blk * 128,
        P3, fccb, (blk == 4) ? cbuf : (unsigned short*)nullptr);
  }

  dim3 gm(R2_ / 64, 12);
  k_meanout<<<gm, 256, 0, stream>>>(cbuf, starts, plist, out);
}